// Round 1
// baseline (387.238 us; speedup 1.0000x reference)
//
#include <hip/hip_runtime.h>
#include <math.h>

typedef unsigned int u32;
typedef unsigned long long u64;

constexpr int N_IMG = 16;
constexpr int C_CLS = 80;
constexpr int H_DIM = 160;
constexpr int W_DIM = 160;
constexpr int L_LOC = H_DIM * W_DIM;   // 25600
constexpr int LC    = L_LOC * C_CLS;   // 2048000
constexpr int K_TOP = 1000;
constexpr int NB    = 8192;            // histogram buckets = top 13 bits of float
constexpr int CAP   = 8192;            // gathered candidates cap per image
constexpr float THRESH = 0.05f;

// ---- workspace layout (bytes) ----
constexpr size_t WS_HIST = 0;                                   // N*NB*4   = 524288
constexpr size_t WS_CNT  = WS_HIST + (size_t)N_IMG * NB * 4;    // N*4
constexpr size_t WS_META = WS_CNT  + (size_t)N_IMG * 4;         // N*4*4 (B1, cand_total, pad, pad)
constexpr size_t WS_KEYS = WS_META + (size_t)N_IMG * 16;        // N*CAP*8 = 1 MiB
constexpr size_t WS_FILL = WS_KEYS + (size_t)N_IMG * CAP * 8;   // N*K*4
constexpr size_t WS_SCTR = WS_FILL + (size_t)N_IMG * K_TOP * 4; // N*L*4
constexpr size_t WS_ZERO_BYTES = WS_KEYS;                       // zero hist+cnt+meta

__device__ inline float sigmoidf_acc(float x) { return 1.0f / (1.0f + expf(-x)); }

// --- kernel 0: sigmoid(centerness), one f32 per location per image ---
__global__ void sctr_kernel(const float* __restrict__ ctr, float* __restrict__ sctr, int n_total) {
    int i = blockIdx.x * blockDim.x + threadIdx.x;
    if (i < n_total) sctr[i] = sigmoidf_acc(ctr[i]);
}

// --- kernel 1: per-image histogram of score key (top 13 bits of float bits) ---
__global__ void hist_kernel(const float* __restrict__ cls, const float* __restrict__ sctr,
                            u32* __restrict__ hist) {
    __shared__ u32 lh[NB];
    const int n = blockIdx.y;
    for (int b = threadIdx.x; b < NB; b += blockDim.x) lh[b] = 0;
    __syncthreads();

    const float4* cls4 = reinterpret_cast<const float4*>(cls + (size_t)n * LC);
    const float* sc_n = sctr + (size_t)n * L_LOC;
    const u32 ngroups = LC / 4;
    const u32 stride = gridDim.x * blockDim.x;
    for (u32 g = blockIdx.x * blockDim.x + threadIdx.x; g < ngroups; g += stride) {
        u32 f = g * 4;
        u32 loc = f % (u32)L_LOC;       // float4 never crosses a class plane (L%4==0)
        float4 x = cls4[g];
        float4 sv = *reinterpret_cast<const float4*>(sc_n + loc);
        float xs[4] = {x.x, x.y, x.z, x.w};
        float ss[4] = {sv.x, sv.y, sv.z, sv.w};
#pragma unroll
        for (int j = 0; j < 4; ++j) {
            float s = sigmoidf_acc(xs[j]);
            if (s > THRESH) {
                float scr = s * ss[j];
                u32 key = __float_as_uint(scr);   // positive floats: bits order == value order
                atomicAdd(&lh[key >> 18], 1u);
            }
        }
    }
    __syncthreads();
    u32* hn = hist + (size_t)n * NB;
    for (int b = threadIdx.x; b < NB; b += blockDim.x) {
        u32 v = lh[b];
        if (v) atomicAdd(&hn[b], v);
    }
}

// --- kernel 2: per-image scan from top bucket to find threshold bucket B1 ---
__global__ void scan_kernel(const u32* __restrict__ hist, u32* __restrict__ meta) {
    __shared__ u32 lh[NB];
    __shared__ u32 part[256];
    const int n = blockIdx.x;
    const int tid = threadIdx.x;
    for (int b = tid; b < NB; b += blockDim.x) lh[b] = hist[(size_t)n * NB + b];
    __syncthreads();
    u32 s = 0;
    for (int b = tid * 32; b < tid * 32 + 32; ++b) s += lh[b];
    part[tid] = s;
    __syncthreads();
    if (tid == 0) {
        u32 total = 0;
        for (int t = 0; t < 256; ++t) total += part[t];
        u32 B1 = 0;
        if (total >= (u32)K_TOP) {
            u32 cum = 0;
            int t = 255;
            for (; t >= 0; --t) {
                if (cum + part[t] >= (u32)K_TOP) break;
                cum += part[t];
            }
            int b = t * 32 + 31;
            for (; b > t * 32; --b) {
                if (cum + lh[b] >= (u32)K_TOP) break;
                cum += lh[b];
            }
            B1 = (u32)b;
        }
        meta[n * 4 + 0] = B1;
        meta[n * 4 + 1] = total;   // total candidate count
    }
}

// --- kernel 3: gather all candidates with key-bucket >= B1 as composite u64 keys ---
__global__ void gather_kernel(const float* __restrict__ cls, const float* __restrict__ sctr,
                              const u32* __restrict__ meta, u32* __restrict__ cnt,
                              u64* __restrict__ keys) {
    const int n = blockIdx.y;
    const u32 keymin = meta[n * 4 + 0] << 18;
    const float4* cls4 = reinterpret_cast<const float4*>(cls + (size_t)n * LC);
    const float* sc_n = sctr + (size_t)n * L_LOC;
    u64* kb = keys + (size_t)n * CAP;
    const u32 ngroups = LC / 4;
    const u32 stride = gridDim.x * blockDim.x;
    for (u32 g = blockIdx.x * blockDim.x + threadIdx.x; g < ngroups; g += stride) {
        u32 f = g * 4;
        u32 c = f / (u32)L_LOC;
        u32 loc = f % (u32)L_LOC;
        float4 x = cls4[g];
        float4 sv = *reinterpret_cast<const float4*>(sc_n + loc);
        float xs[4] = {x.x, x.y, x.z, x.w};
        float ss[4] = {sv.x, sv.y, sv.z, sv.w};
#pragma unroll
        for (int j = 0; j < 4; ++j) {
            float s = sigmoidf_acc(xs[j]);
            if (s > THRESH) {
                float scr = s * ss[j];
                u32 key = __float_as_uint(scr);
                if (key >= keymin) {
                    u32 refidx = (loc + j) * (u32)C_CLS + c;  // flat index in (L,C) order
                    u32 pos = atomicAdd(&cnt[n], 1u);
                    if (pos < (u32)CAP)
                        kb[pos] = ((u64)key << 32) | (u32)(~refidx);  // value desc, idx asc
                }
            }
        }
    }
}

// --- kernel 4 (fallback, no-op in practice): smallest non-candidate flat indices ---
__global__ void fallback_kernel(const float* __restrict__ cls, const u32* __restrict__ meta,
                                u32* __restrict__ fillidx) {
    const int n = blockIdx.x;
    const u32 cand_total = meta[n * 4 + 1];
    if (cand_total >= (u32)K_TOP) return;
    const u32 need = (u32)K_TOP - cand_total;
    __shared__ u32 sc[256];
    __shared__ u32 sfilled;
    if (threadIdx.x == 0) sfilled = 0;
    __syncthreads();
    for (int base = 0; base < LC; base += 256) {
        int idx = base + threadIdx.x;
        u32 flag = 0;
        if (idx < LC) {
            int loc = idx / C_CLS, c = idx - (idx / C_CLS) * C_CLS;
            float x = cls[(size_t)n * LC + (size_t)c * L_LOC + loc];
            flag = (sigmoidf_acc(x) > THRESH) ? 0u : 1u;
        }
        sc[threadIdx.x] = flag;
        __syncthreads();
        for (int off = 1; off < 256; off <<= 1) {
            u32 v = (threadIdx.x >= off) ? sc[threadIdx.x - off] : 0u;
            __syncthreads();
            sc[threadIdx.x] += v;
            __syncthreads();
        }
        u32 excl = sc[threadIdx.x] - flag;
        u32 pos = sfilled + excl;
        if (flag && pos < need) fillidx[(size_t)n * K_TOP + pos] = (u32)idx;
        __syncthreads();
        if (threadIdx.x == 0) sfilled += sc[255];
        __syncthreads();
        if (sfilled >= need) break;
    }
}

// --- kernel 5: per-image bitonic sort of gathered keys + decode/emit outputs ---
__global__ void sort_emit_kernel(const u64* __restrict__ keys, const u32* __restrict__ cnt,
                                 const u32* __restrict__ meta, const u32* __restrict__ fillidx,
                                 const float* __restrict__ locations, const float* __restrict__ breg,
                                 const int* __restrict__ isz, float* __restrict__ out) {
    __shared__ u64 sk[CAP];
    const int n = blockIdx.x;
    const int tid = threadIdx.x;
    u32 M = cnt[n]; if (M > (u32)CAP) M = (u32)CAP;
    const u32 cand_total = meta[n * 4 + 1];
    const u32 cand_slots = cand_total < (u32)K_TOP ? cand_total : (u32)K_TOP;
    u32 n2 = 1024; while (n2 < M) n2 <<= 1;
    const u64* kb = keys + (size_t)n * CAP;
    for (u32 i = tid; i < n2; i += blockDim.x) sk[i] = (i < M) ? kb[i] : 0ull;
    __syncthreads();
    for (u32 k = 2; k <= n2; k <<= 1) {
        for (u32 j = k >> 1; j > 0; j >>= 1) {
            for (u32 i = tid; i < n2; i += blockDim.x) {
                u32 ixj = i ^ j;
                if (ixj > i) {
                    u64 a = sk[i], b = sk[ixj];
                    bool front = ((i & k) == 0);
                    if (front ? (a < b) : (a > b)) { sk[i] = b; sk[ixj] = a; }
                }
            }
            __syncthreads();
        }
    }
    float* ob = out;                                  // boxes  [N,K,4]
    float* os = out + (size_t)N_IMG * K_TOP * 4;      // scores [N,K]
    float* ol = os + (size_t)N_IMG * K_TOP;           // labels [N,K]
    float* ov = ol + (size_t)N_IMG * K_TOP;           // valid  [N,K]
    const float wimg = (float)isz[n * 2 + 1];
    const float himg = (float)isz[n * 2 + 0];
    const float* rn = breg + (size_t)n * 4 * L_LOC;
    for (int k = tid; k < K_TOP; k += blockDim.x) {
        size_t slot = (size_t)n * K_TOP + k;
        if ((u32)k < cand_slots) {
            u64 kk = sk[k];
            u32 vb = (u32)(kk >> 32);
            u32 idx = ~(u32)(kk & 0xFFFFFFFFull);
            float val = __uint_as_float(vb);
            int loc = (int)(idx / (u32)C_CLS);
            int c = (int)(idx - (u32)loc * (u32)C_CLS);
            float lx = locations[loc * 2 + 0], ly = locations[loc * 2 + 1];
            float r0 = rn[0 * L_LOC + loc], r1 = rn[1 * L_LOC + loc];
            float r2 = rn[2 * L_LOC + loc], r3 = rn[3 * L_LOC + loc];
            float x1 = lx - r0, y1 = ly - r1, x2 = lx + r2, y2 = ly + r3;
            x1 = fminf(fmaxf(x1, 0.0f), wimg - 1.0f);
            y1 = fminf(fmaxf(y1, 0.0f), himg - 1.0f);
            x2 = fminf(fmaxf(x2, 0.0f), wimg - 1.0f);
            y2 = fminf(fmaxf(y2, 0.0f), himg - 1.0f);
            float wsz = x2 - x1 + 1.0f, hsz = y2 - y1 + 1.0f;
            bool v = (val > 0.0f) && (wsz >= 0.0f) && (hsz >= 0.0f);  // MIN_SIZE = 0
            float vf = v ? 1.0f : 0.0f;
            ob[slot * 4 + 0] = x1 * vf;
            ob[slot * 4 + 1] = y1 * vf;
            ob[slot * 4 + 2] = x2 * vf;
            ob[slot * 4 + 3] = y2 * vf;
            os[slot] = v ? sqrtf(fmaxf(val, 0.0f)) : 0.0f;
            ol[slot] = (float)(c + 1);
            ov[slot] = vf;
        } else {
            u32 fi = fillidx[(size_t)n * K_TOP + (k - (int)cand_slots)];
            ob[slot * 4 + 0] = 0.0f; ob[slot * 4 + 1] = 0.0f;
            ob[slot * 4 + 2] = 0.0f; ob[slot * 4 + 3] = 0.0f;
            os[slot] = 0.0f;
            ol[slot] = (float)((int)(fi % (u32)C_CLS) + 1);
            ov[slot] = 0.0f;
        }
    }
}

extern "C" void kernel_launch(void* const* d_in, const int* in_sizes, int n_in,
                              void* d_out, int out_size, void* d_ws, size_t ws_size,
                              hipStream_t stream) {
    const float* locations = (const float*)d_in[0];
    const float* cls       = (const float*)d_in[1];
    const float* breg      = (const float*)d_in[2];
    const float* ctr       = (const float*)d_in[3];
    const int*   isz       = (const int*)d_in[4];
    float* out = (float*)d_out;

    char* ws = (char*)d_ws;
    u32* hist = (u32*)(ws + WS_HIST);
    u32* cnt  = (u32*)(ws + WS_CNT);
    u32* meta = (u32*)(ws + WS_META);
    u64* keys = (u64*)(ws + WS_KEYS);
    u32* fill = (u32*)(ws + WS_FILL);
    float* sctr = (float*)(ws + WS_SCTR);

    hipMemsetAsync(ws, 0, WS_ZERO_BYTES, stream);
    sctr_kernel<<<(N_IMG * L_LOC + 255) / 256, 256, 0, stream>>>(ctr, sctr, N_IMG * L_LOC);
    hist_kernel<<<dim3(64, N_IMG), 256, 0, stream>>>(cls, sctr, hist);
    scan_kernel<<<N_IMG, 256, 0, stream>>>(hist, meta);
    gather_kernel<<<dim3(64, N_IMG), 256, 0, stream>>>(cls, sctr, meta, cnt, keys);
    fallback_kernel<<<N_IMG, 256, 0, stream>>>(cls, meta, fill);
    sort_emit_kernel<<<N_IMG, 256, 0, stream>>>(keys, cnt, meta, fill, locations, breg, isz, out);
}

// Round 2
// 184.129 us; speedup vs baseline: 2.1031x; 2.1031x over previous
//
#include <hip/hip_runtime.h>
#include <math.h>

typedef unsigned int u32;
typedef unsigned long long u64;

constexpr int N_IMG = 16;
constexpr int C_CLS = 80;
constexpr int H_DIM = 160;
constexpr int W_DIM = 160;
constexpr int L_LOC = H_DIM * W_DIM;   // 25600
constexpr int LC    = L_LOC * C_CLS;   // 2048000
constexpr int K_TOP = 1000;
constexpr int NB    = 8192;            // histogram buckets
constexpr int CAP   = 8192;            // gathered candidates cap per image
constexpr int GBUF  = 2048;            // per-block LDS gather buffer
constexpr float THRESH = 0.05f;
constexpr u32 KEY_BASE = 119u << 23;   // scores in (0,1): exp field <= 126

// bucket = 13 bits: 3 exponent bits (exp 119..126) + 10 mantissa bits
__device__ inline u32 score_bucket(u32 bits) {
    return (bits >= KEY_BASE) ? ((bits - KEY_BASE) >> 13) : 0u;
}

// ---- workspace layout (bytes) ----
constexpr size_t WS_HIST = 0;                                   // N*NB*4   = 524288
constexpr size_t WS_CNT  = WS_HIST + (size_t)N_IMG * NB * 4;    // N*4
constexpr size_t WS_META = WS_CNT  + (size_t)N_IMG * 4;         // N*4*4 (keymin, cand_total)
constexpr size_t WS_KEYS = WS_META + (size_t)N_IMG * 16;        // N*CAP*8 = 1 MiB
constexpr size_t WS_FILL = WS_KEYS + (size_t)N_IMG * CAP * 8;   // N*K*4
constexpr size_t WS_SCTR = WS_FILL + (size_t)N_IMG * K_TOP * 4; // N*L*4
constexpr size_t WS_ZERO_BYTES = WS_KEYS;                       // zero hist+cnt+meta

__device__ inline float sigmoidf_acc(float x) { return 1.0f / (1.0f + expf(-x)); }

// --- kernel 0: sigmoid(centerness) ---
__global__ void sctr_kernel(const float* __restrict__ ctr, float* __restrict__ sctr, int n_total) {
    int i = blockIdx.x * blockDim.x + threadIdx.x;
    if (i < n_total) sctr[i] = sigmoidf_acc(ctr[i]);
}

// --- kernel 1: per-image histogram of score bucket ---
__global__ void hist_kernel(const float* __restrict__ cls, const float* __restrict__ sctr,
                            u32* __restrict__ hist) {
    __shared__ u32 lh[NB];
    const int n = blockIdx.y;
    for (int b = threadIdx.x; b < NB; b += blockDim.x) lh[b] = 0;
    __syncthreads();

    const float4* cls4 = reinterpret_cast<const float4*>(cls + (size_t)n * LC);
    const float* sc_n = sctr + (size_t)n * L_LOC;
    const u32 ngroups = LC / 4;
    const u32 stride = gridDim.x * blockDim.x;
    for (u32 g = blockIdx.x * blockDim.x + threadIdx.x; g < ngroups; g += stride) {
        u32 f = g * 4;
        u32 loc = f % (u32)L_LOC;       // float4 never crosses a class plane (L%4==0)
        float4 x = cls4[g];
        float4 sv = *reinterpret_cast<const float4*>(sc_n + loc);
        float xs[4] = {x.x, x.y, x.z, x.w};
        float ss[4] = {sv.x, sv.y, sv.z, sv.w};
#pragma unroll
        for (int j = 0; j < 4; ++j) {
            float s = sigmoidf_acc(xs[j]);
            if (s > THRESH) {
                float scr = s * ss[j];
                atomicAdd(&lh[score_bucket(__float_as_uint(scr))], 1u);
            }
        }
    }
    __syncthreads();
    u32* hn = hist + (size_t)n * NB;
    for (int b = threadIdx.x; b < NB; b += blockDim.x) {
        u32 v = lh[b];
        if (v) atomicAdd(&hn[b], v);
    }
}

// --- kernel 2: per-image scan from top bucket: find threshold bucket -> keymin ---
__global__ void scan_kernel(const u32* __restrict__ hist, u32* __restrict__ meta) {
    __shared__ u32 lh[NB];
    __shared__ u32 part[256];
    const int n = blockIdx.x;
    const int tid = threadIdx.x;
    for (int b = tid; b < NB; b += blockDim.x) lh[b] = hist[(size_t)n * NB + b];
    __syncthreads();
    u32 s = 0;
    for (int b = tid * 32; b < tid * 32 + 32; ++b) s += lh[b];
    part[tid] = s;
    __syncthreads();
    if (tid == 0) {
        u32 total = 0;
        for (int t = 0; t < 256; ++t) total += part[t];
        u32 B1 = 0;
        if (total >= (u32)K_TOP) {
            u32 cum = 0;
            int t = 255;
            for (; t >= 0; --t) {
                if (cum + part[t] >= (u32)K_TOP) break;
                cum += part[t];
            }
            int b = t * 32 + 31;
            for (; b > t * 32; --b) {
                if (cum + lh[b] >= (u32)K_TOP) break;
                cum += lh[b];
            }
            B1 = (u32)b;
        }
        meta[n * 4 + 0] = B1 ? ((B1 << 13) + KEY_BASE) : 0u;  // keymin in float-bit space
        meta[n * 4 + 1] = total;                              // total candidate count
    }
}

// --- kernel 3: gather candidates with score-bits >= keymin; LDS-buffered compaction ---
__global__ void gather_kernel(const float* __restrict__ cls, const float* __restrict__ sctr,
                              const u32* __restrict__ meta, u32* __restrict__ cnt,
                              u64* __restrict__ keys) {
    __shared__ u64 buf[GBUF];
    __shared__ u32 lcnt;
    __shared__ u32 gbase;
    const int n = blockIdx.y;
    if (threadIdx.x == 0) lcnt = 0;
    __syncthreads();
    const u32 keymin = meta[n * 4 + 0];
    const float4* cls4 = reinterpret_cast<const float4*>(cls + (size_t)n * LC);
    const float* sc_n = sctr + (size_t)n * L_LOC;
    const u32 ngroups = LC / 4;
    const u32 stride = gridDim.x * blockDim.x;
    for (u32 g = blockIdx.x * blockDim.x + threadIdx.x; g < ngroups; g += stride) {
        u32 f = g * 4;
        u32 c = f / (u32)L_LOC;
        u32 loc = f % (u32)L_LOC;
        float4 x = cls4[g];
        float4 sv = *reinterpret_cast<const float4*>(sc_n + loc);
        float xs[4] = {x.x, x.y, x.z, x.w};
        float ss[4] = {sv.x, sv.y, sv.z, sv.w};
#pragma unroll
        for (int j = 0; j < 4; ++j) {
            float s = sigmoidf_acc(xs[j]);
            if (s > THRESH) {
                float scr = s * ss[j];
                u32 key = __float_as_uint(scr);
                if (key >= keymin) {
                    u32 refidx = (loc + j) * (u32)C_CLS + c;  // flat index in (L,C) order
                    u32 pos = atomicAdd(&lcnt, 1u);
                    if (pos < (u32)GBUF)
                        buf[pos] = ((u64)key << 32) | (u32)(~refidx);  // value desc, idx asc
                }
            }
        }
    }
    __syncthreads();
    u32 m = lcnt; if (m > (u32)GBUF) m = (u32)GBUF;
    if (threadIdx.x == 0) gbase = m ? atomicAdd(&cnt[n], m) : 0u;
    __syncthreads();
    u64* kb = keys + (size_t)n * CAP;
    for (u32 i = threadIdx.x; i < m; i += blockDim.x) {
        u32 pos = gbase + i;
        if (pos < (u32)CAP) kb[pos] = buf[i];
    }
}

// --- kernel 4 (fallback, no-op in practice): smallest non-candidate flat indices ---
__global__ void fallback_kernel(const float* __restrict__ cls, const u32* __restrict__ meta,
                                u32* __restrict__ fillidx) {
    const int n = blockIdx.x;
    const u32 cand_total = meta[n * 4 + 1];
    if (cand_total >= (u32)K_TOP) return;
    const u32 need = (u32)K_TOP - cand_total;
    __shared__ u32 sc[256];
    __shared__ u32 sfilled;
    if (threadIdx.x == 0) sfilled = 0;
    __syncthreads();
    for (int base = 0; base < LC; base += 256) {
        int idx = base + threadIdx.x;
        u32 flag = 0;
        if (idx < LC) {
            int loc = idx / C_CLS, c = idx - (idx / C_CLS) * C_CLS;
            float x = cls[(size_t)n * LC + (size_t)c * L_LOC + loc];
            flag = (sigmoidf_acc(x) > THRESH) ? 0u : 1u;
        }
        sc[threadIdx.x] = flag;
        __syncthreads();
        for (int off = 1; off < 256; off <<= 1) {
            u32 v = (threadIdx.x >= off) ? sc[threadIdx.x - off] : 0u;
            __syncthreads();
            sc[threadIdx.x] += v;
            __syncthreads();
        }
        u32 excl = sc[threadIdx.x] - flag;
        u32 pos = sfilled + excl;
        if (flag && pos < need) fillidx[(size_t)n * K_TOP + pos] = (u32)idx;
        __syncthreads();
        if (threadIdx.x == 0) sfilled += sc[255];
        __syncthreads();
        if (sfilled >= need) break;
    }
}

// --- kernel 5: per-image bitonic sort of gathered keys + decode/emit outputs ---
__global__ void sort_emit_kernel(const u64* __restrict__ keys, const u32* __restrict__ cnt,
                                 const u32* __restrict__ meta, const u32* __restrict__ fillidx,
                                 const float* __restrict__ locations, const float* __restrict__ breg,
                                 const int* __restrict__ isz, float* __restrict__ out) {
    __shared__ u64 sk[CAP];
    const int n = blockIdx.x;
    const int tid = threadIdx.x;
    u32 M = cnt[n]; if (M > (u32)CAP) M = (u32)CAP;
    const u32 cand_total = meta[n * 4 + 1];
    const u32 cand_slots = cand_total < (u32)K_TOP ? cand_total : (u32)K_TOP;
    u32 n2 = 1024; while (n2 < M) n2 <<= 1;
    const u64* kb = keys + (size_t)n * CAP;
    for (u32 i = tid; i < n2; i += blockDim.x) sk[i] = (i < M) ? kb[i] : 0ull;
    __syncthreads();
    for (u32 k = 2; k <= n2; k <<= 1) {
        for (u32 j = k >> 1; j > 0; j >>= 1) {
            for (u32 i = tid; i < n2; i += blockDim.x) {
                u32 ixj = i ^ j;
                if (ixj > i) {
                    u64 a = sk[i], b = sk[ixj];
                    bool front = ((i & k) == 0);
                    if (front ? (a < b) : (a > b)) { sk[i] = b; sk[ixj] = a; }
                }
            }
            __syncthreads();
        }
    }
    float* ob = out;                                  // boxes  [N,K,4]
    float* os = out + (size_t)N_IMG * K_TOP * 4;      // scores [N,K]
    float* ol = os + (size_t)N_IMG * K_TOP;           // labels [N,K]
    float* ov = ol + (size_t)N_IMG * K_TOP;           // valid  [N,K]
    const float wimg = (float)isz[n * 2 + 1];
    const float himg = (float)isz[n * 2 + 0];
    const float* rn = breg + (size_t)n * 4 * L_LOC;
    for (int k = tid; k < K_TOP; k += blockDim.x) {
        size_t slot = (size_t)n * K_TOP + k;
        if ((u32)k < cand_slots) {
            u64 kk = sk[k];
            u32 vb = (u32)(kk >> 32);
            u32 idx = ~(u32)(kk & 0xFFFFFFFFull);
            float val = __uint_as_float(vb);
            int loc = (int)(idx / (u32)C_CLS);
            int c = (int)(idx - (u32)loc * (u32)C_CLS);
            float lx = locations[loc * 2 + 0], ly = locations[loc * 2 + 1];
            float r0 = rn[0 * L_LOC + loc], r1 = rn[1 * L_LOC + loc];
            float r2 = rn[2 * L_LOC + loc], r3 = rn[3 * L_LOC + loc];
            float x1 = lx - r0, y1 = ly - r1, x2 = lx + r2, y2 = ly + r3;
            x1 = fminf(fmaxf(x1, 0.0f), wimg - 1.0f);
            y1 = fminf(fmaxf(y1, 0.0f), himg - 1.0f);
            x2 = fminf(fmaxf(x2, 0.0f), wimg - 1.0f);
            y2 = fminf(fmaxf(y2, 0.0f), himg - 1.0f);
            float wsz = x2 - x1 + 1.0f, hsz = y2 - y1 + 1.0f;
            bool v = (val > 0.0f) && (wsz >= 0.0f) && (hsz >= 0.0f);  // MIN_SIZE = 0
            float vf = v ? 1.0f : 0.0f;
            ob[slot * 4 + 0] = x1 * vf;
            ob[slot * 4 + 1] = y1 * vf;
            ob[slot * 4 + 2] = x2 * vf;
            ob[slot * 4 + 3] = y2 * vf;
            os[slot] = v ? sqrtf(fmaxf(val, 0.0f)) : 0.0f;
            ol[slot] = (float)(c + 1);
            ov[slot] = vf;
        } else {
            u32 fi = fillidx[(size_t)n * K_TOP + (k - (int)cand_slots)];
            ob[slot * 4 + 0] = 0.0f; ob[slot * 4 + 1] = 0.0f;
            ob[slot * 4 + 2] = 0.0f; ob[slot * 4 + 3] = 0.0f;
            os[slot] = 0.0f;
            ol[slot] = (float)((int)(fi % (u32)C_CLS) + 1);
            ov[slot] = 0.0f;
        }
    }
}

extern "C" void kernel_launch(void* const* d_in, const int* in_sizes, int n_in,
                              void* d_out, int out_size, void* d_ws, size_t ws_size,
                              hipStream_t stream) {
    const float* locations = (const float*)d_in[0];
    const float* cls       = (const float*)d_in[1];
    const float* breg      = (const float*)d_in[2];
    const float* ctr       = (const float*)d_in[3];
    const int*   isz       = (const int*)d_in[4];
    float* out = (float*)d_out;

    char* ws = (char*)d_ws;
    u32* hist = (u32*)(ws + WS_HIST);
    u32* cnt  = (u32*)(ws + WS_CNT);
    u32* meta = (u32*)(ws + WS_META);
    u64* keys = (u64*)(ws + WS_KEYS);
    u32* fill = (u32*)(ws + WS_FILL);
    float* sctr = (float*)(ws + WS_SCTR);

    hipMemsetAsync(ws, 0, WS_ZERO_BYTES, stream);
    sctr_kernel<<<(N_IMG * L_LOC + 255) / 256, 256, 0, stream>>>(ctr, sctr, N_IMG * L_LOC);
    hist_kernel<<<dim3(128, N_IMG), 256, 0, stream>>>(cls, sctr, hist);
    scan_kernel<<<N_IMG, 256, 0, stream>>>(hist, meta);
    gather_kernel<<<dim3(128, N_IMG), 256, 0, stream>>>(cls, sctr, meta, cnt, keys);
    fallback_kernel<<<N_IMG, 256, 0, stream>>>(cls, meta, fill);
    sort_emit_kernel<<<N_IMG, 256, 0, stream>>>(keys, cnt, meta, fill, locations, breg, isz, out);
}

// Round 3
// 162.734 us; speedup vs baseline: 2.3796x; 1.1315x over previous
//
#include <hip/hip_runtime.h>
#include <math.h>

typedef unsigned int u32;
typedef unsigned long long u64;

constexpr int N_IMG = 16;
constexpr int C_CLS = 80;
constexpr int H_DIM = 160;
constexpr int W_DIM = 160;
constexpr int L_LOC = H_DIM * W_DIM;   // 25600
constexpr int LC    = L_LOC * C_CLS;   // 2048000
constexpr int K_TOP = 1000;
constexpr int NB    = 1024;            // histogram buckets (3 exp + 7 mantissa bits)
constexpr int NBLK  = 64;              // passA blocks per image
constexpr int CAP   = 8192;            // final gathered candidates cap per image
constexpr int CAP_SPEC = 32768;        // speculative list cap per image
constexpr int GBUF_SPEC = 1024;        // per-block LDS spec buffer
constexpr float THRESH = 0.05f;
constexpr u32 KEY_BASE = 119u << 23;   // bucket 0 below 2^-8
constexpr u32 T0_BITS  = 0x3F333333u;  // 0.70f — speculative gather threshold

__device__ inline u32 score_bucket(u32 bits) {
    return (bits >= KEY_BASE) ? ((bits - KEY_BASE) >> 16) : 0u;  // 0..1023
}

// ---- workspace layout (bytes) ----
constexpr size_t WS_CNT   = 0;                                        // N*4
constexpr size_t WS_SCNT  = 64;                                       // N*4
constexpr size_t WS_OFLOW = 128;                                      // N*4
constexpr size_t WS_META  = 192;                                      // N*16 (keymin, total, mode, pad)
constexpr size_t WS_ZERO  = 512;
constexpr size_t WS_HIST  = 512;                                      // N*NBLK*NB*4 = 4 MiB
constexpr size_t WS_SPEC  = WS_HIST + (size_t)N_IMG * NBLK * NB * 4;  // N*CAP_SPEC*8 = 4 MiB
constexpr size_t WS_KEYS  = WS_SPEC + (size_t)N_IMG * CAP_SPEC * 8;   // N*CAP*8 = 1 MiB
constexpr size_t WS_FILL  = WS_KEYS + (size_t)N_IMG * CAP * 8;        // N*K*4
constexpr size_t WS_SCTR  = WS_FILL + (size_t)N_IMG * K_TOP * 4;      // N*L*4

__device__ inline float sigmoidf_acc(float x) { return 1.0f / (1.0f + expf(-x)); }

// --- kernel 0: sigmoid(centerness) ---
__global__ void sctr_kernel(const float* __restrict__ ctr, float* __restrict__ sctr, int n_total) {
    int i = blockIdx.x * blockDim.x + threadIdx.x;
    if (i < n_total) sctr[i] = sigmoidf_acc(ctr[i]);
}

// --- kernel 1 (pass A): fused histogram + speculative gather (score >= 0.70) ---
__global__ __launch_bounds__(256) void passA_kernel(
        const float* __restrict__ cls, const float* __restrict__ sctr,
        u32* __restrict__ Hsub, u64* __restrict__ spec,
        u32* __restrict__ scnt, u32* __restrict__ oflow) {
    __shared__ u32 lh[NB];
    __shared__ u64 sbuf[GBUF_SPEC];
    __shared__ u32 lcnt;
    __shared__ u32 gbase;
    const int n = blockIdx.y;
    for (int b = threadIdx.x; b < NB; b += blockDim.x) lh[b] = 0;
    if (threadIdx.x == 0) lcnt = 0;
    __syncthreads();

    const float4* cls4 = reinterpret_cast<const float4*>(cls + (size_t)n * LC);
    const float* sc_n = sctr + (size_t)n * L_LOC;
    const u32 ngroups = LC / 4;
    const u32 stride = gridDim.x * blockDim.x;
    for (u32 g = blockIdx.x * blockDim.x + threadIdx.x; g < ngroups; g += stride) {
        u32 f = g * 4;
        u32 c = f / (u32)L_LOC;
        u32 loc = f % (u32)L_LOC;       // float4 never crosses a class plane (L%4==0)
        float4 x = cls4[g];
        float4 sv = *reinterpret_cast<const float4*>(sc_n + loc);
        float xs[4] = {x.x, x.y, x.z, x.w};
        float ss[4] = {sv.x, sv.y, sv.z, sv.w};
#pragma unroll
        for (int j = 0; j < 4; ++j) {
            float s = sigmoidf_acc(xs[j]);
            if (s > THRESH) {
                float scr = s * ss[j];
                u32 bits = __float_as_uint(scr);
                atomicAdd(&lh[score_bucket(bits)], 1u);
                if (bits >= T0_BITS) {
                    u32 refidx = (loc + j) * (u32)C_CLS + c;
                    u32 pos = atomicAdd(&lcnt, 1u);
                    if (pos < (u32)GBUF_SPEC)
                        sbuf[pos] = ((u64)bits << 32) | (u32)(~refidx);  // value desc, idx asc
                }
            }
        }
    }
    __syncthreads();
    // non-atomic per-block histogram dump (coalesced)
    u32* hb = Hsub + ((size_t)n * NBLK + blockIdx.x) * NB;
    for (int b = threadIdx.x; b < NB; b += blockDim.x) hb[b] = lh[b];
    // spec list merge: one global atomic per block
    u32 m = lcnt;
    bool of = (m > (u32)GBUF_SPEC);
    if (of) m = (u32)GBUF_SPEC;
    if (threadIdx.x == 0) {
        gbase = m ? atomicAdd(&scnt[n], m) : 0u;
        if (of) atomicOr(&oflow[n], 1u);
    }
    __syncthreads();
    u64* sp = spec + (size_t)n * CAP_SPEC;
    for (u32 i = threadIdx.x; i < m; i += blockDim.x) {
        u32 pos = gbase + i;
        if (pos < (u32)CAP_SPEC) sp[pos] = sbuf[i];
    }
}

// --- kernel 2: reduce sub-histograms, find keymin, decide FAST/SLOW mode ---
__global__ void scan_kernel(const u32* __restrict__ Hsub, const u32* __restrict__ scnt,
                            const u32* __restrict__ oflow, u32* __restrict__ meta) {
    __shared__ u32 lh[NB];
    __shared__ u32 part[256];
    const int n = blockIdx.x;
    const int tid = threadIdx.x;
    for (int b = tid; b < NB; b += blockDim.x) {
        u32 s = 0;
        for (int blk = 0; blk < NBLK; ++blk)
            s += Hsub[((size_t)n * NBLK + blk) * NB + b];
        lh[b] = s;
    }
    __syncthreads();
    part[tid] = lh[tid * 4] + lh[tid * 4 + 1] + lh[tid * 4 + 2] + lh[tid * 4 + 3];
    __syncthreads();
    if (tid == 0) {
        u32 total = 0;
        for (int t = 0; t < 256; ++t) total += part[t];
        u32 B1 = 0;
        if (total >= (u32)K_TOP) {
            u32 cum = 0;
            int t = 255;
            for (; t >= 0; --t) {
                if (cum + part[t] >= (u32)K_TOP) break;
                cum += part[t];
            }
            int b = t * 4 + 3;
            for (; b > t * 4; --b) {
                if (cum + lh[b] >= (u32)K_TOP) break;
                cum += lh[b];
            }
            B1 = (u32)b;
        }
        u32 keymin = B1 ? (KEY_BASE + (B1 << 16)) : 0u;
        u32 mode = (keymin >= T0_BITS && oflow[n] == 0u && scnt[n] <= (u32)CAP_SPEC) ? 1u : 0u;
        meta[n * 4 + 0] = keymin;
        meta[n * 4 + 1] = total;
        meta[n * 4 + 2] = mode;
    }
}

// --- kernel 3 (FAST): filter the speculative list by keymin ---
__global__ void filter_fast_kernel(const u64* __restrict__ spec, const u32* __restrict__ scnt,
                                   const u32* __restrict__ meta, u32* __restrict__ cnt,
                                   u64* __restrict__ keys) {
    const int n = blockIdx.x;
    if (meta[n * 4 + 2] == 0u) return;
    __shared__ u32 lcnt;
    if (threadIdx.x == 0) lcnt = 0;
    __syncthreads();
    const u32 keymin = meta[n * 4 + 0];
    u32 M = scnt[n]; if (M > (u32)CAP_SPEC) M = (u32)CAP_SPEC;
    const u64* sp = spec + (size_t)n * CAP_SPEC;
    u64* kb = keys + (size_t)n * CAP;
    for (u32 i = threadIdx.x; i < M; i += blockDim.x) {
        u64 e = sp[i];
        if ((u32)(e >> 32) >= keymin) {
            u32 p = atomicAdd(&lcnt, 1u);
            if (p < (u32)CAP) kb[p] = e;
        }
    }
    __syncthreads();
    if (threadIdx.x == 0) cnt[n] = (lcnt < (u32)CAP) ? lcnt : (u32)CAP;
}

// --- kernel 4 (SLOW, early-exits in practice): full re-read gather ---
__global__ __launch_bounds__(256) void gather_slow_kernel(
        const float* __restrict__ cls, const float* __restrict__ sctr,
        const u32* __restrict__ meta, u32* __restrict__ cnt, u64* __restrict__ keys) {
    const int n = blockIdx.y;
    if (meta[n * 4 + 2] != 0u) return;
    __shared__ u64 buf[GBUF_SPEC];
    __shared__ u32 lcnt;
    __shared__ u32 gbase;
    if (threadIdx.x == 0) lcnt = 0;
    __syncthreads();
    const u32 keymin = meta[n * 4 + 0];
    const float4* cls4 = reinterpret_cast<const float4*>(cls + (size_t)n * LC);
    const float* sc_n = sctr + (size_t)n * L_LOC;
    const u32 ngroups = LC / 4;
    const u32 stride = gridDim.x * blockDim.x;
    for (u32 g = blockIdx.x * blockDim.x + threadIdx.x; g < ngroups; g += stride) {
        u32 f = g * 4;
        u32 c = f / (u32)L_LOC;
        u32 loc = f % (u32)L_LOC;
        float4 x = cls4[g];
        float4 sv = *reinterpret_cast<const float4*>(sc_n + loc);
        float xs[4] = {x.x, x.y, x.z, x.w};
        float ss[4] = {sv.x, sv.y, sv.z, sv.w};
#pragma unroll
        for (int j = 0; j < 4; ++j) {
            float s = sigmoidf_acc(xs[j]);
            if (s > THRESH) {
                float scr = s * ss[j];
                u32 bits = __float_as_uint(scr);
                if (bits >= keymin) {
                    u32 refidx = (loc + j) * (u32)C_CLS + c;
                    u32 pos = atomicAdd(&lcnt, 1u);
                    if (pos < (u32)GBUF_SPEC)
                        buf[pos] = ((u64)bits << 32) | (u32)(~refidx);
                }
            }
        }
    }
    __syncthreads();
    u32 m = lcnt; if (m > (u32)GBUF_SPEC) m = (u32)GBUF_SPEC;
    if (threadIdx.x == 0) gbase = m ? atomicAdd(&cnt[n], m) : 0u;
    __syncthreads();
    u64* kb = keys + (size_t)n * CAP;
    for (u32 i = threadIdx.x; i < m; i += blockDim.x) {
        u32 pos = gbase + i;
        if (pos < (u32)CAP) kb[pos] = buf[i];
    }
}

// --- kernel 5 (fallback, no-op in practice): smallest non-candidate flat indices ---
__global__ void fallback_kernel(const float* __restrict__ cls, const u32* __restrict__ meta,
                                u32* __restrict__ fillidx) {
    const int n = blockIdx.x;
    const u32 cand_total = meta[n * 4 + 1];
    if (cand_total >= (u32)K_TOP) return;
    const u32 need = (u32)K_TOP - cand_total;
    __shared__ u32 sc[256];
    __shared__ u32 sfilled;
    if (threadIdx.x == 0) sfilled = 0;
    __syncthreads();
    for (int base = 0; base < LC; base += 256) {
        int idx = base + threadIdx.x;
        u32 flag = 0;
        if (idx < LC) {
            int loc = idx / C_CLS, c = idx - (idx / C_CLS) * C_CLS;
            float x = cls[(size_t)n * LC + (size_t)c * L_LOC + loc];
            flag = (sigmoidf_acc(x) > THRESH) ? 0u : 1u;
        }
        sc[threadIdx.x] = flag;
        __syncthreads();
        for (int off = 1; off < 256; off <<= 1) {
            u32 v = (threadIdx.x >= off) ? sc[threadIdx.x - off] : 0u;
            __syncthreads();
            sc[threadIdx.x] += v;
            __syncthreads();
        }
        u32 excl = sc[threadIdx.x] - flag;
        u32 pos = sfilled + excl;
        if (flag && pos < need) fillidx[(size_t)n * K_TOP + pos] = (u32)idx;
        __syncthreads();
        if (threadIdx.x == 0) sfilled += sc[255];
        __syncthreads();
        if (sfilled >= need) break;
    }
}

// --- kernel 6: per-image bitonic sort of gathered keys + decode/emit outputs ---
__global__ void sort_emit_kernel(const u64* __restrict__ keys, const u32* __restrict__ cnt,
                                 const u32* __restrict__ meta, const u32* __restrict__ fillidx,
                                 const float* __restrict__ locations, const float* __restrict__ breg,
                                 const int* __restrict__ isz, float* __restrict__ out) {
    __shared__ u64 sk[CAP];
    const int n = blockIdx.x;
    const int tid = threadIdx.x;
    u32 M = cnt[n]; if (M > (u32)CAP) M = (u32)CAP;
    const u32 cand_total = meta[n * 4 + 1];
    const u32 cand_slots = cand_total < (u32)K_TOP ? cand_total : (u32)K_TOP;
    u32 n2 = 1024; while (n2 < M) n2 <<= 1;
    const u64* kb = keys + (size_t)n * CAP;
    for (u32 i = tid; i < n2; i += blockDim.x) sk[i] = (i < M) ? kb[i] : 0ull;
    __syncthreads();
    for (u32 k = 2; k <= n2; k <<= 1) {
        for (u32 j = k >> 1; j > 0; j >>= 1) {
            for (u32 i = tid; i < n2; i += blockDim.x) {
                u32 ixj = i ^ j;
                if (ixj > i) {
                    u64 a = sk[i], b = sk[ixj];
                    bool front = ((i & k) == 0);
                    if (front ? (a < b) : (a > b)) { sk[i] = b; sk[ixj] = a; }
                }
            }
            __syncthreads();
        }
    }
    float* ob = out;                                  // boxes  [N,K,4]
    float* os = out + (size_t)N_IMG * K_TOP * 4;      // scores [N,K]
    float* ol = os + (size_t)N_IMG * K_TOP;           // labels [N,K]
    float* ov = ol + (size_t)N_IMG * K_TOP;           // valid  [N,K]
    const float wimg = (float)isz[n * 2 + 1];
    const float himg = (float)isz[n * 2 + 0];
    const float* rn = breg + (size_t)n * 4 * L_LOC;
    for (int k = tid; k < K_TOP; k += blockDim.x) {
        size_t slot = (size_t)n * K_TOP + k;
        if ((u32)k < cand_slots) {
            u64 kk = sk[k];
            u32 vb = (u32)(kk >> 32);
            u32 idx = ~(u32)(kk & 0xFFFFFFFFull);
            float val = __uint_as_float(vb);
            int loc = (int)(idx / (u32)C_CLS);
            int c = (int)(idx - (u32)loc * (u32)C_CLS);
            float lx = locations[loc * 2 + 0], ly = locations[loc * 2 + 1];
            float r0 = rn[0 * L_LOC + loc], r1 = rn[1 * L_LOC + loc];
            float r2 = rn[2 * L_LOC + loc], r3 = rn[3 * L_LOC + loc];
            float x1 = lx - r0, y1 = ly - r1, x2 = lx + r2, y2 = ly + r3;
            x1 = fminf(fmaxf(x1, 0.0f), wimg - 1.0f);
            y1 = fminf(fmaxf(y1, 0.0f), himg - 1.0f);
            x2 = fminf(fmaxf(x2, 0.0f), wimg - 1.0f);
            y2 = fminf(fmaxf(y2, 0.0f), himg - 1.0f);
            float wsz = x2 - x1 + 1.0f, hsz = y2 - y1 + 1.0f;
            bool v = (val > 0.0f) && (wsz >= 0.0f) && (hsz >= 0.0f);  // MIN_SIZE = 0
            float vf = v ? 1.0f : 0.0f;
            ob[slot * 4 + 0] = x1 * vf;
            ob[slot * 4 + 1] = y1 * vf;
            ob[slot * 4 + 2] = x2 * vf;
            ob[slot * 4 + 3] = y2 * vf;
            os[slot] = v ? sqrtf(fmaxf(val, 0.0f)) : 0.0f;
            ol[slot] = (float)(c + 1);
            ov[slot] = vf;
        } else {
            u32 fi = fillidx[(size_t)n * K_TOP + (k - (int)cand_slots)];
            ob[slot * 4 + 0] = 0.0f; ob[slot * 4 + 1] = 0.0f;
            ob[slot * 4 + 2] = 0.0f; ob[slot * 4 + 3] = 0.0f;
            os[slot] = 0.0f;
            ol[slot] = (float)((int)(fi % (u32)C_CLS) + 1);
            ov[slot] = 0.0f;
        }
    }
}

extern "C" void kernel_launch(void* const* d_in, const int* in_sizes, int n_in,
                              void* d_out, int out_size, void* d_ws, size_t ws_size,
                              hipStream_t stream) {
    const float* locations = (const float*)d_in[0];
    const float* cls       = (const float*)d_in[1];
    const float* breg      = (const float*)d_in[2];
    const float* ctr       = (const float*)d_in[3];
    const int*   isz       = (const int*)d_in[4];
    float* out = (float*)d_out;

    char* ws = (char*)d_ws;
    u32* cnt   = (u32*)(ws + WS_CNT);
    u32* scnt  = (u32*)(ws + WS_SCNT);
    u32* oflow = (u32*)(ws + WS_OFLOW);
    u32* meta  = (u32*)(ws + WS_META);
    u32* Hsub  = (u32*)(ws + WS_HIST);
    u64* spec  = (u64*)(ws + WS_SPEC);
    u64* keys  = (u64*)(ws + WS_KEYS);
    u32* fill  = (u32*)(ws + WS_FILL);
    float* sctr = (float*)(ws + WS_SCTR);

    hipMemsetAsync(ws, 0, WS_ZERO, stream);
    sctr_kernel<<<(N_IMG * L_LOC + 255) / 256, 256, 0, stream>>>(ctr, sctr, N_IMG * L_LOC);
    passA_kernel<<<dim3(NBLK, N_IMG), 256, 0, stream>>>(cls, sctr, Hsub, spec, scnt, oflow);
    scan_kernel<<<N_IMG, 256, 0, stream>>>(Hsub, scnt, oflow, meta);
    filter_fast_kernel<<<N_IMG, 512, 0, stream>>>(spec, scnt, meta, cnt, keys);
    gather_slow_kernel<<<dim3(NBLK, N_IMG), 256, 0, stream>>>(cls, sctr, meta, cnt, keys);
    fallback_kernel<<<N_IMG, 256, 0, stream>>>(cls, meta, fill);
    sort_emit_kernel<<<N_IMG, 512, 0, stream>>>(keys, cnt, meta, fill, locations, breg, isz, out);
}

// Round 4
// 159.724 us; speedup vs baseline: 2.4244x; 1.0188x over previous
//
#include <hip/hip_runtime.h>
#include <math.h>

typedef unsigned int u32;
typedef unsigned long long u64;

constexpr int N_IMG = 16;
constexpr int C_CLS = 80;
constexpr int H_DIM = 160;
constexpr int W_DIM = 160;
constexpr int L_LOC = H_DIM * W_DIM;   // 25600
constexpr int LC    = L_LOC * C_CLS;   // 2048000
constexpr int K_TOP = 1000;
constexpr int NB    = 1024;            // histogram buckets (bits-KEY_BASE)>>16
constexpr int NBLK  = 64;              // slow-path hist blocks per image
constexpr int CAP   = 8192;            // final candidate cap per image
constexpr int CAP_SPEC = 32768;        // speculative list cap per image
constexpr int GBUF  = 1024;            // passA per-block LDS spec buffer (u32)
constexpr int GBUF_SLOW = 2048;        // gather_slow LDS u64 buffer
constexpr float THRESH = 0.05f;
constexpr u32 KEY_BASE = 119u << 23;
constexpr u32 T0_BITS  = 0x3F333333u;  // bits of 0.7f
constexpr float T0     = 0.7f;
constexpr float DELTA  = 0.05f;        // conservative slack in logit space

__device__ inline u32 score_bucket(u32 bits) {
    return (bits >= KEY_BASE) ? ((bits - KEY_BASE) >> 16) : 0u;  // 0..1023
}

// ---- workspace layout (bytes) ----
constexpr size_t WS_CNT   = 0;                                        // N*4
constexpr size_t WS_SCNT  = 64;                                       // N*4
constexpr size_t WS_OFLOW = 128;                                      // N*4
constexpr size_t WS_META  = 192;                                      // N*16 (keymin,total,done)
constexpr size_t WS_ZERO  = 512;
// Hsub (slow) and keys2 (fast) overlay: per-image 256 KB each, mutually exclusive
constexpr size_t WS_HIST  = 512;                                      // 16*64*1024*4 = 4 MiB
constexpr size_t WS_SPEC  = WS_HIST + (size_t)N_IMG * NBLK * NB * 4;  // 16*32768*4 = 2 MiB
constexpr size_t WS_KEYS  = WS_SPEC + (size_t)N_IMG * CAP_SPEC * 4;   // 16*8192*8 = 1 MiB
constexpr size_t WS_FILL  = WS_KEYS + (size_t)N_IMG * CAP * 8;        // N*K*4
constexpr size_t WS_SCTR  = WS_FILL + (size_t)N_IMG * K_TOP * 4;      // N*L*4
constexpr size_t WS_XMIN  = WS_SCTR + (size_t)N_IMG * L_LOC * 4;      // N*L*4

__device__ inline float sigmoidf_acc(float x) { return 1.0f / (1.0f + expf(-x)); }

// --- kernel 0: sigmoid(centerness) + per-location logit threshold xmin ---
__global__ void prep_kernel(const float* __restrict__ ctr, float* __restrict__ sctr,
                            float* __restrict__ xmin, int n_total) {
    int i = blockIdx.x * blockDim.x + threadIdx.x;
    if (i >= n_total) return;
    float s = sigmoidf_acc(ctr[i]);
    sctr[i] = s;
    float t = T0 / s;                       // need sigmoid(x) >= t for score >= T0
    float xm;
    if (t >= 1.0f) xm = 3.0e38f;            // impossible at this location
    else xm = logf(t / (1.0f - t)) - DELTA; // logit(t) with conservative slack
    xmin[i] = xm;
}

// --- kernel 1 (hot pass): one compare per element; append refidx of survivors ---
__global__ __launch_bounds__(256) void passA_kernel(
        const float* __restrict__ cls, const float* __restrict__ xmin,
        u32* __restrict__ spec, u32* __restrict__ scnt, u32* __restrict__ oflow) {
    __shared__ u32 sbuf[GBUF];
    __shared__ u32 lcnt, gbase, lof;
    const int n = blockIdx.y;
    if (threadIdx.x == 0) { lcnt = 0; lof = 0; }
    __syncthreads();
    const float4* cls4 = reinterpret_cast<const float4*>(cls + (size_t)n * LC);
    const float* xm_n = xmin + (size_t)n * L_LOC;
    const u32 ngroups = LC / 4;
    const u32 stride = gridDim.x * blockDim.x;
    for (u32 g = blockIdx.x * blockDim.x + threadIdx.x; g < ngroups; g += stride) {
        u32 f = g * 4;
        u32 c = f / (u32)L_LOC;
        u32 loc = f % (u32)L_LOC;           // float4 never crosses a class plane (L%4==0)
        float4 x = cls4[g];
        float4 m = *reinterpret_cast<const float4*>(xm_n + loc);
        u32 base = loc * (u32)C_CLS + c;    // refidx for j=0; +C_CLS per j
        if (x.x >= m.x) { u32 p = atomicAdd(&lcnt, 1u); if (p < (u32)GBUF) sbuf[p] = base;             else lof = 1; }
        if (x.y >= m.y) { u32 p = atomicAdd(&lcnt, 1u); if (p < (u32)GBUF) sbuf[p] = base + C_CLS;     else lof = 1; }
        if (x.z >= m.z) { u32 p = atomicAdd(&lcnt, 1u); if (p < (u32)GBUF) sbuf[p] = base + 2 * C_CLS; else lof = 1; }
        if (x.w >= m.w) { u32 p = atomicAdd(&lcnt, 1u); if (p < (u32)GBUF) sbuf[p] = base + 3 * C_CLS; else lof = 1; }
    }
    __syncthreads();
    u32 m_ = lcnt > (u32)GBUF ? (u32)GBUF : lcnt;
    if (threadIdx.x == 0) {
        gbase = m_ ? atomicAdd(&scnt[n], m_) : 0u;
        if (lof || lcnt > (u32)GBUF) atomicOr(&oflow[n], 1u);
        if (m_ && gbase + m_ > (u32)CAP_SPEC) atomicOr(&oflow[n], 1u);
    }
    __syncthreads();
    u32* sp = spec + (size_t)n * CAP_SPEC;
    for (u32 i = threadIdx.x; i < m_; i += blockDim.x) {
        u32 pos = gbase + i;
        if (pos < (u32)CAP_SPEC) sp[pos] = sbuf[i];
    }
}

// --- kernel 2 (FAST finisher): exact scores of spec, rank-K cutoff, filter ---
__global__ __launch_bounds__(1024) void filterB_kernel(
        const float* __restrict__ cls, const float* __restrict__ sctr,
        const u32* __restrict__ spec, const u32* __restrict__ scnt,
        const u32* __restrict__ oflow, u64* __restrict__ keys2,
        u64* __restrict__ keys, u32* __restrict__ cnt, u32* __restrict__ meta) {
    __shared__ u32 lh[NB];
    __shared__ u32 part[256];
    __shared__ u32 s_cex, s_keymin, s_ok, s_lcnt;
    const int n = blockIdx.x;
    const int tid = threadIdx.x;
    if (oflow[n]) return;                         // uniform: slow path handles
    for (int b = tid; b < NB; b += blockDim.x) lh[b] = 0;
    if (tid == 0) { s_cex = 0; s_lcnt = 0; s_ok = 0; }
    __syncthreads();
    u32 M = scnt[n]; if (M > (u32)CAP_SPEC) M = (u32)CAP_SPEC;
    const float* cls_n = cls + (size_t)n * LC;
    const float* sc_n = sctr + (size_t)n * L_LOC;
    const u32* sp = spec + (size_t)n * CAP_SPEC;
    u64* k2 = keys2 + (size_t)n * CAP_SPEC;
    u32 cex = 0;
    for (u32 i = tid; i < M; i += blockDim.x) {
        u32 r = sp[i];
        u32 loc = r / (u32)C_CLS;
        u32 c = r - loc * (u32)C_CLS;
        float x = cls_n[(size_t)c * L_LOC + loc];
        float s = sigmoidf_acc(x);                // exact same formula as reference path
        float scr = s * sc_n[loc];
        u32 bits = __float_as_uint(scr);
        k2[i] = ((u64)bits << 32) | (u32)(~r);    // value desc, idx asc
        atomicAdd(&lh[score_bucket(bits)], 1u);
        if (bits >= T0_BITS) cex++;
    }
    if (cex) atomicAdd(&s_cex, cex);
    __syncthreads();
    if (tid < 256) part[tid] = lh[tid * 4] + lh[tid * 4 + 1] + lh[tid * 4 + 2] + lh[tid * 4 + 3];
    __syncthreads();
    if (tid == 0) {
        u32 cum = 0; int t = 255;
        for (; t >= 0; --t) {
            if (cum + part[t] >= (u32)K_TOP) break;
            cum += part[t];
        }
        if (t >= 0) {
            int b = t * 4 + 3;
            for (; b > t * 4; --b) {
                if (cum + lh[b] >= (u32)K_TOP) break;
                cum += lh[b];
            }
            cum += lh[b];                          // count of spec >= bucket b
            u32 keymin = KEY_BASE + ((u32)b << 16);
            if (keymin < T0_BITS) keymin = T0_BITS;  // spec superset only guaranteed >= T0
            // FAST valid iff top-K all have exact score >= T0 and filtered set fits
            if (s_cex >= (u32)K_TOP && cum <= (u32)CAP) {
                s_keymin = keymin; s_ok = 1;
                meta[n * 4 + 0] = keymin;
                meta[n * 4 + 1] = (u32)LC;         // total >= K; fallback not needed
                meta[n * 4 + 2] = 1u;              // done
            }
        }
    }
    __syncthreads();
    if (!s_ok) return;
    const u32 keymin = s_keymin;
    u64* kb = keys + (size_t)n * CAP;
    for (u32 i = tid; i < M; i += blockDim.x) {
        u64 e = k2[i];
        if ((u32)(e >> 32) >= keymin) {
            u32 p = atomicAdd(&s_lcnt, 1u);
            if (p < (u32)CAP) kb[p] = e;
        }
    }
    __syncthreads();
    if (tid == 0) cnt[n] = s_lcnt < (u32)CAP ? s_lcnt : (u32)CAP;
}

// --- kernel 3 (SLOW, gated): full histogram of exact scores ---
__global__ __launch_bounds__(256) void slow_hist_kernel(
        const float* __restrict__ cls, const float* __restrict__ sctr,
        const u32* __restrict__ meta, u32* __restrict__ Hsub) {
    const int n = blockIdx.y;
    if (meta[n * 4 + 2] != 0u) return;
    __shared__ u32 lh[NB];
    for (int b = threadIdx.x; b < NB; b += blockDim.x) lh[b] = 0;
    __syncthreads();
    const float4* cls4 = reinterpret_cast<const float4*>(cls + (size_t)n * LC);
    const float* sc_n = sctr + (size_t)n * L_LOC;
    const u32 ngroups = LC / 4;
    const u32 stride = gridDim.x * blockDim.x;
    for (u32 g = blockIdx.x * blockDim.x + threadIdx.x; g < ngroups; g += stride) {
        u32 f = g * 4;
        u32 loc = f % (u32)L_LOC;
        float4 x = cls4[g];
        float4 sv = *reinterpret_cast<const float4*>(sc_n + loc);
        float xs[4] = {x.x, x.y, x.z, x.w};
        float ss[4] = {sv.x, sv.y, sv.z, sv.w};
#pragma unroll
        for (int j = 0; j < 4; ++j) {
            float s = sigmoidf_acc(xs[j]);
            if (s > THRESH) {
                float scr = s * ss[j];
                atomicAdd(&lh[score_bucket(__float_as_uint(scr))], 1u);
            }
        }
    }
    __syncthreads();
    u32* hb = Hsub + ((size_t)n * NBLK + blockIdx.x) * NB;
    for (int b = threadIdx.x; b < NB; b += blockDim.x) hb[b] = lh[b];
}

// --- kernel 4 (SLOW, gated): reduce sub-histograms -> keymin, total ---
__global__ void slow_scan_kernel(const u32* __restrict__ Hsub, u32* __restrict__ meta) {
    const int n = blockIdx.x;
    if (meta[n * 4 + 2] != 0u) return;
    __shared__ u32 lh[NB];
    __shared__ u32 part[256];
    const int tid = threadIdx.x;
    for (int b = tid; b < NB; b += blockDim.x) {
        u32 s = 0;
        for (int blk = 0; blk < NBLK; ++blk)
            s += Hsub[((size_t)n * NBLK + blk) * NB + b];
        lh[b] = s;
    }
    __syncthreads();
    part[tid] = lh[tid * 4] + lh[tid * 4 + 1] + lh[tid * 4 + 2] + lh[tid * 4 + 3];
    __syncthreads();
    if (tid == 0) {
        u32 total = 0;
        for (int t = 0; t < 256; ++t) total += part[t];
        u32 B1 = 0;
        if (total >= (u32)K_TOP) {
            u32 cum = 0;
            int t = 255;
            for (; t >= 0; --t) {
                if (cum + part[t] >= (u32)K_TOP) break;
                cum += part[t];
            }
            int b = t * 4 + 3;
            for (; b > t * 4; --b) {
                if (cum + lh[b] >= (u32)K_TOP) break;
                cum += lh[b];
            }
            B1 = (u32)b;
        }
        meta[n * 4 + 0] = B1 ? (KEY_BASE + (B1 << 16)) : 0u;
        meta[n * 4 + 1] = total;
    }
}

// --- kernel 5 (SLOW, gated): full re-read gather with exact scores ---
__global__ __launch_bounds__(256) void gather_slow_kernel(
        const float* __restrict__ cls, const float* __restrict__ sctr,
        const u32* __restrict__ meta, u32* __restrict__ cnt, u64* __restrict__ keys) {
    const int n = blockIdx.y;
    if (meta[n * 4 + 2] != 0u) return;
    __shared__ u64 buf[GBUF_SLOW];
    __shared__ u32 lcnt, gbase;
    if (threadIdx.x == 0) lcnt = 0;
    __syncthreads();
    const u32 keymin = meta[n * 4 + 0];
    const float4* cls4 = reinterpret_cast<const float4*>(cls + (size_t)n * LC);
    const float* sc_n = sctr + (size_t)n * L_LOC;
    const u32 ngroups = LC / 4;
    const u32 stride = gridDim.x * blockDim.x;
    for (u32 g = blockIdx.x * blockDim.x + threadIdx.x; g < ngroups; g += stride) {
        u32 f = g * 4;
        u32 c = f / (u32)L_LOC;
        u32 loc = f % (u32)L_LOC;
        float4 x = cls4[g];
        float4 sv = *reinterpret_cast<const float4*>(sc_n + loc);
        float xs[4] = {x.x, x.y, x.z, x.w};
        float ss[4] = {sv.x, sv.y, sv.z, sv.w};
#pragma unroll
        for (int j = 0; j < 4; ++j) {
            float s = sigmoidf_acc(xs[j]);
            if (s > THRESH) {
                float scr = s * ss[j];
                u32 bits = __float_as_uint(scr);
                if (bits >= keymin) {
                    u32 refidx = (loc + j) * (u32)C_CLS + c;
                    u32 pos = atomicAdd(&lcnt, 1u);
                    if (pos < (u32)GBUF_SLOW)
                        buf[pos] = ((u64)bits << 32) | (u32)(~refidx);
                }
            }
        }
    }
    __syncthreads();
    u32 m = lcnt; if (m > (u32)GBUF_SLOW) m = (u32)GBUF_SLOW;
    if (threadIdx.x == 0) gbase = m ? atomicAdd(&cnt[n], m) : 0u;
    __syncthreads();
    u64* kb = keys + (size_t)n * CAP;
    for (u32 i = threadIdx.x; i < m; i += blockDim.x) {
        u32 pos = gbase + i;
        if (pos < (u32)CAP) kb[pos] = buf[i];
    }
}

// --- kernel 6 (fallback, gated; no-op in practice) ---
__global__ void fallback_kernel(const float* __restrict__ cls, const u32* __restrict__ meta,
                                u32* __restrict__ fillidx) {
    const int n = blockIdx.x;
    const u32 cand_total = meta[n * 4 + 1];
    if (cand_total >= (u32)K_TOP) return;
    const u32 need = (u32)K_TOP - cand_total;
    __shared__ u32 sc[256];
    __shared__ u32 sfilled;
    if (threadIdx.x == 0) sfilled = 0;
    __syncthreads();
    for (int base = 0; base < LC; base += 256) {
        int idx = base + threadIdx.x;
        u32 flag = 0;
        if (idx < LC) {
            int loc = idx / C_CLS, c = idx - (idx / C_CLS) * C_CLS;
            float x = cls[(size_t)n * LC + (size_t)c * L_LOC + loc];
            flag = (sigmoidf_acc(x) > THRESH) ? 0u : 1u;
        }
        sc[threadIdx.x] = flag;
        __syncthreads();
        for (int off = 1; off < 256; off <<= 1) {
            u32 v = (threadIdx.x >= off) ? sc[threadIdx.x - off] : 0u;
            __syncthreads();
            sc[threadIdx.x] += v;
            __syncthreads();
        }
        u32 excl = sc[threadIdx.x] - flag;
        u32 pos = sfilled + excl;
        if (flag && pos < need) fillidx[(size_t)n * K_TOP + pos] = (u32)idx;
        __syncthreads();
        if (threadIdx.x == 0) sfilled += sc[255];
        __syncthreads();
        if (sfilled >= need) break;
    }
}

// --- kernel 7: per-image bitonic sort + decode/emit ---
__global__ void sort_emit_kernel(const u64* __restrict__ keys, const u32* __restrict__ cnt,
                                 const u32* __restrict__ meta, const u32* __restrict__ fillidx,
                                 const float* __restrict__ locations, const float* __restrict__ breg,
                                 const int* __restrict__ isz, float* __restrict__ out) {
    __shared__ u64 sk[CAP];
    const int n = blockIdx.x;
    const int tid = threadIdx.x;
    u32 M = cnt[n]; if (M > (u32)CAP) M = (u32)CAP;
    const u32 cand_total = meta[n * 4 + 1];
    const u32 cand_slots = cand_total < (u32)K_TOP ? cand_total : (u32)K_TOP;
    u32 n2 = 1024; while (n2 < M) n2 <<= 1;
    const u64* kb = keys + (size_t)n * CAP;
    for (u32 i = tid; i < n2; i += blockDim.x) sk[i] = (i < M) ? kb[i] : 0ull;
    __syncthreads();
    for (u32 k = 2; k <= n2; k <<= 1) {
        for (u32 j = k >> 1; j > 0; j >>= 1) {
            for (u32 i = tid; i < n2; i += blockDim.x) {
                u32 ixj = i ^ j;
                if (ixj > i) {
                    u64 a = sk[i], b = sk[ixj];
                    bool front = ((i & k) == 0);
                    if (front ? (a < b) : (a > b)) { sk[i] = b; sk[ixj] = a; }
                }
            }
            __syncthreads();
        }
    }
    float* ob = out;                                  // boxes  [N,K,4]
    float* os = out + (size_t)N_IMG * K_TOP * 4;      // scores [N,K]
    float* ol = os + (size_t)N_IMG * K_TOP;           // labels [N,K]
    float* ov = ol + (size_t)N_IMG * K_TOP;           // valid  [N,K]
    const float wimg = (float)isz[n * 2 + 1];
    const float himg = (float)isz[n * 2 + 0];
    const float* rn = breg + (size_t)n * 4 * L_LOC;
    for (int k = tid; k < K_TOP; k += blockDim.x) {
        size_t slot = (size_t)n * K_TOP + k;
        if ((u32)k < cand_slots) {
            u64 kk = sk[k];
            u32 vb = (u32)(kk >> 32);
            u32 idx = ~(u32)(kk & 0xFFFFFFFFull);
            float val = __uint_as_float(vb);
            int loc = (int)(idx / (u32)C_CLS);
            int c = (int)(idx - (u32)loc * (u32)C_CLS);
            float lx = locations[loc * 2 + 0], ly = locations[loc * 2 + 1];
            float r0 = rn[0 * L_LOC + loc], r1 = rn[1 * L_LOC + loc];
            float r2 = rn[2 * L_LOC + loc], r3 = rn[3 * L_LOC + loc];
            float x1 = lx - r0, y1 = ly - r1, x2 = lx + r2, y2 = ly + r3;
            x1 = fminf(fmaxf(x1, 0.0f), wimg - 1.0f);
            y1 = fminf(fmaxf(y1, 0.0f), himg - 1.0f);
            x2 = fminf(fmaxf(x2, 0.0f), wimg - 1.0f);
            y2 = fminf(fmaxf(y2, 0.0f), himg - 1.0f);
            float wsz = x2 - x1 + 1.0f, hsz = y2 - y1 + 1.0f;
            bool v = (val > 0.0f) && (wsz >= 0.0f) && (hsz >= 0.0f);  // MIN_SIZE = 0
            float vf = v ? 1.0f : 0.0f;
            ob[slot * 4 + 0] = x1 * vf;
            ob[slot * 4 + 1] = y1 * vf;
            ob[slot * 4 + 2] = x2 * vf;
            ob[slot * 4 + 3] = y2 * vf;
            os[slot] = v ? sqrtf(fmaxf(val, 0.0f)) : 0.0f;
            ol[slot] = (float)(c + 1);
            ov[slot] = vf;
        } else {
            u32 fi = fillidx[(size_t)n * K_TOP + (k - (int)cand_slots)];
            ob[slot * 4 + 0] = 0.0f; ob[slot * 4 + 1] = 0.0f;
            ob[slot * 4 + 2] = 0.0f; ob[slot * 4 + 3] = 0.0f;
            os[slot] = 0.0f;
            ol[slot] = (float)((int)(fi % (u32)C_CLS) + 1);
            ov[slot] = 0.0f;
        }
    }
}

extern "C" void kernel_launch(void* const* d_in, const int* in_sizes, int n_in,
                              void* d_out, int out_size, void* d_ws, size_t ws_size,
                              hipStream_t stream) {
    const float* locations = (const float*)d_in[0];
    const float* cls       = (const float*)d_in[1];
    const float* breg      = (const float*)d_in[2];
    const float* ctr       = (const float*)d_in[3];
    const int*   isz       = (const int*)d_in[4];
    float* out = (float*)d_out;

    char* ws = (char*)d_ws;
    u32* cnt   = (u32*)(ws + WS_CNT);
    u32* scnt  = (u32*)(ws + WS_SCNT);
    u32* oflow = (u32*)(ws + WS_OFLOW);
    u32* meta  = (u32*)(ws + WS_META);
    u32* Hsub  = (u32*)(ws + WS_HIST);   // slow path
    u64* keys2 = (u64*)(ws + WS_HIST);   // fast path (overlay; per-image exclusive)
    u32* spec  = (u32*)(ws + WS_SPEC);
    u64* keys  = (u64*)(ws + WS_KEYS);
    u32* fill  = (u32*)(ws + WS_FILL);
    float* sctr = (float*)(ws + WS_SCTR);
    float* xmin = (float*)(ws + WS_XMIN);

    hipMemsetAsync(ws, 0, WS_ZERO, stream);
    prep_kernel<<<(N_IMG * L_LOC + 255) / 256, 256, 0, stream>>>(ctr, sctr, xmin, N_IMG * L_LOC);
    passA_kernel<<<dim3(128, N_IMG), 256, 0, stream>>>(cls, xmin, spec, scnt, oflow);
    filterB_kernel<<<N_IMG, 1024, 0, stream>>>(cls, sctr, spec, scnt, oflow, keys2, keys, cnt, meta);
    slow_hist_kernel<<<dim3(NBLK, N_IMG), 256, 0, stream>>>(cls, sctr, meta, Hsub);
    slow_scan_kernel<<<N_IMG, 256, 0, stream>>>(Hsub, meta);
    gather_slow_kernel<<<dim3(NBLK, N_IMG), 256, 0, stream>>>(cls, sctr, meta, cnt, keys);
    fallback_kernel<<<N_IMG, 256, 0, stream>>>(cls, meta, fill);
    sort_emit_kernel<<<N_IMG, 512, 0, stream>>>(keys, cnt, meta, fill, locations, breg, isz, out);
}

// Round 5
// 146.437 us; speedup vs baseline: 2.6444x; 1.0907x over previous
//
#include <hip/hip_runtime.h>
#include <math.h>

typedef unsigned int u32;
typedef unsigned long long u64;

constexpr int N_IMG = 16;
constexpr int C_CLS = 80;
constexpr int H_DIM = 160;
constexpr int W_DIM = 160;
constexpr int L_LOC = H_DIM * W_DIM;   // 25600
constexpr int LC    = L_LOC * C_CLS;   // 2048000
constexpr int K_TOP = 1000;
constexpr int NB    = 1024;            // histogram buckets (bits-KEY_BASE)>>16
constexpr int NBLK  = 64;              // slow-path hist blocks per image
constexpr int CAP   = 8192;            // final candidate cap per image
constexpr int CAP_SPEC = 32768;        // speculative list cap per image
constexpr int GBUF  = 1024;            // passA per-block LDS spec buffer (u32)
constexpr int GBUF_SLOW = 2048;        // gather_slow LDS u64 buffer
constexpr float THRESH = 0.05f;
constexpr u32 KEY_BASE = 119u << 23;
constexpr u32 T0_BITS  = 0x3F333333u;  // bits of 0.7f
constexpr float T0     = 0.7f;
constexpr float DELTA  = 0.05f;        // conservative slack in logit space

__device__ inline u32 score_bucket(u32 bits) {
    return (bits >= KEY_BASE) ? ((bits - KEY_BASE) >> 16) : 0u;  // 0..1023
}

// ---- workspace layout (bytes) ----
constexpr size_t WS_CNT   = 0;                                        // N*4
constexpr size_t WS_SCNT  = 64;                                       // N*4
constexpr size_t WS_OFLOW = 128;                                      // N*4
constexpr size_t WS_META  = 192;                                      // N*16 (keymin,total,done)
constexpr size_t WS_ZERO  = 512;
// Hsub (slow) and keys2 (fast) overlay: per-image 256 KB each, mutually exclusive
constexpr size_t WS_HIST  = 512;                                      // 16*64*1024*4 = 4 MiB
constexpr size_t WS_SPEC  = WS_HIST + (size_t)N_IMG * NBLK * NB * 4;  // 16*32768*4 = 2 MiB
constexpr size_t WS_KEYS  = WS_SPEC + (size_t)N_IMG * CAP_SPEC * 4;   // 16*8192*8 = 1 MiB
constexpr size_t WS_FILL  = WS_KEYS + (size_t)N_IMG * CAP * 8;        // N*K*4
constexpr size_t WS_SCTR  = WS_FILL + (size_t)N_IMG * K_TOP * 4;      // N*L*4
constexpr size_t WS_XMIN  = WS_SCTR + (size_t)N_IMG * L_LOC * 4;      // N*L*4

__device__ inline float sigmoidf_acc(float x) { return 1.0f / (1.0f + expf(-x)); }

// --- kernel -1: zero the 512-byte control block (replaces hipMemsetAsync:
//     a 512-B memset node cost ~73 us/replay as a fillBufferAligned graph node) ---
__global__ void zero_kernel(u32* __restrict__ ws32) {
    if (threadIdx.x < (int)(WS_ZERO / 4)) ws32[threadIdx.x] = 0u;
}

// --- kernel 0: sigmoid(centerness) + per-location logit threshold xmin ---
__global__ void prep_kernel(const float* __restrict__ ctr, float* __restrict__ sctr,
                            float* __restrict__ xmin, int n_total) {
    int i = blockIdx.x * blockDim.x + threadIdx.x;
    if (i >= n_total) return;
    float s = sigmoidf_acc(ctr[i]);
    sctr[i] = s;
    float t = T0 / s;                       // need sigmoid(x) >= t for score >= T0
    float xm;
    if (t >= 1.0f) xm = 3.0e38f;            // impossible at this location
    else xm = logf(t / (1.0f - t)) - DELTA; // logit(t) with conservative slack
    xmin[i] = xm;
}

// --- kernel 1 (hot pass): one compare per element; append refidx of survivors ---
__global__ __launch_bounds__(256) void passA_kernel(
        const float* __restrict__ cls, const float* __restrict__ xmin,
        u32* __restrict__ spec, u32* __restrict__ scnt, u32* __restrict__ oflow) {
    __shared__ u32 sbuf[GBUF];
    __shared__ u32 lcnt, gbase, lof;
    const int n = blockIdx.y;
    if (threadIdx.x == 0) { lcnt = 0; lof = 0; }
    __syncthreads();
    const float4* cls4 = reinterpret_cast<const float4*>(cls + (size_t)n * LC);
    const float* xm_n = xmin + (size_t)n * L_LOC;
    const u32 ngroups = LC / 4;
    const u32 stride = gridDim.x * blockDim.x;
    for (u32 g = blockIdx.x * blockDim.x + threadIdx.x; g < ngroups; g += stride) {
        u32 f = g * 4;
        u32 c = f / (u32)L_LOC;
        u32 loc = f % (u32)L_LOC;           // float4 never crosses a class plane (L%4==0)
        float4 x = cls4[g];
        float4 m = *reinterpret_cast<const float4*>(xm_n + loc);
        u32 base = loc * (u32)C_CLS + c;    // refidx for j=0; +C_CLS per j
        if (x.x >= m.x) { u32 p = atomicAdd(&lcnt, 1u); if (p < (u32)GBUF) sbuf[p] = base;             else lof = 1; }
        if (x.y >= m.y) { u32 p = atomicAdd(&lcnt, 1u); if (p < (u32)GBUF) sbuf[p] = base + C_CLS;     else lof = 1; }
        if (x.z >= m.z) { u32 p = atomicAdd(&lcnt, 1u); if (p < (u32)GBUF) sbuf[p] = base + 2 * C_CLS; else lof = 1; }
        if (x.w >= m.w) { u32 p = atomicAdd(&lcnt, 1u); if (p < (u32)GBUF) sbuf[p] = base + 3 * C_CLS; else lof = 1; }
    }
    __syncthreads();
    u32 m_ = lcnt > (u32)GBUF ? (u32)GBUF : lcnt;
    if (threadIdx.x == 0) {
        gbase = m_ ? atomicAdd(&scnt[n], m_) : 0u;
        if (lof || lcnt > (u32)GBUF) atomicOr(&oflow[n], 1u);
        if (m_ && gbase + m_ > (u32)CAP_SPEC) atomicOr(&oflow[n], 1u);
    }
    __syncthreads();
    u32* sp = spec + (size_t)n * CAP_SPEC;
    for (u32 i = threadIdx.x; i < m_; i += blockDim.x) {
        u32 pos = gbase + i;
        if (pos < (u32)CAP_SPEC) sp[pos] = sbuf[i];
    }
}

// --- kernel 2 (FAST finisher): exact scores of spec, rank-K cutoff, filter ---
__global__ __launch_bounds__(1024) void filterB_kernel(
        const float* __restrict__ cls, const float* __restrict__ sctr,
        const u32* __restrict__ spec, const u32* __restrict__ scnt,
        const u32* __restrict__ oflow, u64* __restrict__ keys2,
        u64* __restrict__ keys, u32* __restrict__ cnt, u32* __restrict__ meta) {
    __shared__ u32 lh[NB];
    __shared__ u32 part[256];
    __shared__ u32 s_cex, s_keymin, s_ok, s_lcnt;
    const int n = blockIdx.x;
    const int tid = threadIdx.x;
    if (oflow[n]) return;                         // uniform: slow path handles
    for (int b = tid; b < NB; b += blockDim.x) lh[b] = 0;
    if (tid == 0) { s_cex = 0; s_lcnt = 0; s_ok = 0; }
    __syncthreads();
    u32 M = scnt[n]; if (M > (u32)CAP_SPEC) M = (u32)CAP_SPEC;
    const float* cls_n = cls + (size_t)n * LC;
    const float* sc_n = sctr + (size_t)n * L_LOC;
    const u32* sp = spec + (size_t)n * CAP_SPEC;
    u64* k2 = keys2 + (size_t)n * CAP_SPEC;
    u32 cex = 0;
    for (u32 i = tid; i < M; i += blockDim.x) {
        u32 r = sp[i];
        u32 loc = r / (u32)C_CLS;
        u32 c = r - loc * (u32)C_CLS;
        float x = cls_n[(size_t)c * L_LOC + loc];
        float s = sigmoidf_acc(x);                // exact same formula as reference path
        float scr = s * sc_n[loc];
        u32 bits = __float_as_uint(scr);
        k2[i] = ((u64)bits << 32) | (u32)(~r);    // value desc, idx asc
        atomicAdd(&lh[score_bucket(bits)], 1u);
        if (bits >= T0_BITS) cex++;
    }
    if (cex) atomicAdd(&s_cex, cex);
    __syncthreads();
    if (tid < 256) part[tid] = lh[tid * 4] + lh[tid * 4 + 1] + lh[tid * 4 + 2] + lh[tid * 4 + 3];
    __syncthreads();
    if (tid == 0) {
        u32 cum = 0; int t = 255;
        for (; t >= 0; --t) {
            if (cum + part[t] >= (u32)K_TOP) break;
            cum += part[t];
        }
        if (t >= 0) {
            int b = t * 4 + 3;
            for (; b > t * 4; --b) {
                if (cum + lh[b] >= (u32)K_TOP) break;
                cum += lh[b];
            }
            cum += lh[b];                          // count of spec >= bucket b
            u32 keymin = KEY_BASE + ((u32)b << 16);
            if (keymin < T0_BITS) keymin = T0_BITS;  // spec superset only guaranteed >= T0
            // FAST valid iff top-K all have exact score >= T0 and filtered set fits
            if (s_cex >= (u32)K_TOP && cum <= (u32)CAP) {
                s_keymin = keymin; s_ok = 1;
                meta[n * 4 + 0] = keymin;
                meta[n * 4 + 1] = (u32)LC;         // total >= K; fallback not needed
                meta[n * 4 + 2] = 1u;              // done
            }
        }
    }
    __syncthreads();
    if (!s_ok) return;
    const u32 keymin = s_keymin;
    u64* kb = keys + (size_t)n * CAP;
    for (u32 i = tid; i < M; i += blockDim.x) {
        u64 e = k2[i];
        if ((u32)(e >> 32) >= keymin) {
            u32 p = atomicAdd(&s_lcnt, 1u);
            if (p < (u32)CAP) kb[p] = e;
        }
    }
    __syncthreads();
    if (tid == 0) cnt[n] = s_lcnt < (u32)CAP ? s_lcnt : (u32)CAP;
}

// --- kernel 3 (SLOW, gated): full histogram of exact scores ---
__global__ __launch_bounds__(256) void slow_hist_kernel(
        const float* __restrict__ cls, const float* __restrict__ sctr,
        const u32* __restrict__ meta, u32* __restrict__ Hsub) {
    const int n = blockIdx.y;
    if (meta[n * 4 + 2] != 0u) return;
    __shared__ u32 lh[NB];
    for (int b = threadIdx.x; b < NB; b += blockDim.x) lh[b] = 0;
    __syncthreads();
    const float4* cls4 = reinterpret_cast<const float4*>(cls + (size_t)n * LC);
    const float* sc_n = sctr + (size_t)n * L_LOC;
    const u32 ngroups = LC / 4;
    const u32 stride = gridDim.x * blockDim.x;
    for (u32 g = blockIdx.x * blockDim.x + threadIdx.x; g < ngroups; g += stride) {
        u32 f = g * 4;
        u32 loc = f % (u32)L_LOC;
        float4 x = cls4[g];
        float4 sv = *reinterpret_cast<const float4*>(sc_n + loc);
        float xs[4] = {x.x, x.y, x.z, x.w};
        float ss[4] = {sv.x, sv.y, sv.z, sv.w};
#pragma unroll
        for (int j = 0; j < 4; ++j) {
            float s = sigmoidf_acc(xs[j]);
            if (s > THRESH) {
                float scr = s * ss[j];
                atomicAdd(&lh[score_bucket(__float_as_uint(scr))], 1u);
            }
        }
    }
    __syncthreads();
    u32* hb = Hsub + ((size_t)n * NBLK + blockIdx.x) * NB;
    for (int b = threadIdx.x; b < NB; b += blockDim.x) hb[b] = lh[b];
}

// --- kernel 4 (SLOW, gated): reduce sub-histograms -> keymin, total ---
__global__ void slow_scan_kernel(const u32* __restrict__ Hsub, u32* __restrict__ meta) {
    const int n = blockIdx.x;
    if (meta[n * 4 + 2] != 0u) return;
    __shared__ u32 lh[NB];
    __shared__ u32 part[256];
    const int tid = threadIdx.x;
    for (int b = tid; b < NB; b += blockDim.x) {
        u32 s = 0;
        for (int blk = 0; blk < NBLK; ++blk)
            s += Hsub[((size_t)n * NBLK + blk) * NB + b];
        lh[b] = s;
    }
    __syncthreads();
    part[tid] = lh[tid * 4] + lh[tid * 4 + 1] + lh[tid * 4 + 2] + lh[tid * 4 + 3];
    __syncthreads();
    if (tid == 0) {
        u32 total = 0;
        for (int t = 0; t < 256; ++t) total += part[t];
        u32 B1 = 0;
        if (total >= (u32)K_TOP) {
            u32 cum = 0;
            int t = 255;
            for (; t >= 0; --t) {
                if (cum + part[t] >= (u32)K_TOP) break;
                cum += part[t];
            }
            int b = t * 4 + 3;
            for (; b > t * 4; --b) {
                if (cum + lh[b] >= (u32)K_TOP) break;
                cum += lh[b];
            }
            B1 = (u32)b;
        }
        meta[n * 4 + 0] = B1 ? (KEY_BASE + (B1 << 16)) : 0u;
        meta[n * 4 + 1] = total;
    }
}

// --- kernel 5 (SLOW, gated): full re-read gather with exact scores ---
__global__ __launch_bounds__(256) void gather_slow_kernel(
        const float* __restrict__ cls, const float* __restrict__ sctr,
        const u32* __restrict__ meta, u32* __restrict__ cnt, u64* __restrict__ keys) {
    const int n = blockIdx.y;
    if (meta[n * 4 + 2] != 0u) return;
    __shared__ u64 buf[GBUF_SLOW];
    __shared__ u32 lcnt, gbase;
    if (threadIdx.x == 0) lcnt = 0;
    __syncthreads();
    const u32 keymin = meta[n * 4 + 0];
    const float4* cls4 = reinterpret_cast<const float4*>(cls + (size_t)n * LC);
    const float* sc_n = sctr + (size_t)n * L_LOC;
    const u32 ngroups = LC / 4;
    const u32 stride = gridDim.x * blockDim.x;
    for (u32 g = blockIdx.x * blockDim.x + threadIdx.x; g < ngroups; g += stride) {
        u32 f = g * 4;
        u32 c = f / (u32)L_LOC;
        u32 loc = f % (u32)L_LOC;
        float4 x = cls4[g];
        float4 sv = *reinterpret_cast<const float4*>(sc_n + loc);
        float xs[4] = {x.x, x.y, x.z, x.w};
        float ss[4] = {sv.x, sv.y, sv.z, sv.w};
#pragma unroll
        for (int j = 0; j < 4; ++j) {
            float s = sigmoidf_acc(xs[j]);
            if (s > THRESH) {
                float scr = s * ss[j];
                u32 bits = __float_as_uint(scr);
                if (bits >= keymin) {
                    u32 refidx = (loc + j) * (u32)C_CLS + c;
                    u32 pos = atomicAdd(&lcnt, 1u);
                    if (pos < (u32)GBUF_SLOW)
                        buf[pos] = ((u64)bits << 32) | (u32)(~refidx);
                }
            }
        }
    }
    __syncthreads();
    u32 m = lcnt; if (m > (u32)GBUF_SLOW) m = (u32)GBUF_SLOW;
    if (threadIdx.x == 0) gbase = m ? atomicAdd(&cnt[n], m) : 0u;
    __syncthreads();
    u64* kb = keys + (size_t)n * CAP;
    for (u32 i = threadIdx.x; i < m; i += blockDim.x) {
        u32 pos = gbase + i;
        if (pos < (u32)CAP) kb[pos] = buf[i];
    }
}

// --- kernel 6 (fallback, gated; no-op in practice) ---
__global__ void fallback_kernel(const float* __restrict__ cls, const u32* __restrict__ meta,
                                u32* __restrict__ fillidx) {
    const int n = blockIdx.x;
    const u32 cand_total = meta[n * 4 + 1];
    if (cand_total >= (u32)K_TOP) return;
    const u32 need = (u32)K_TOP - cand_total;
    __shared__ u32 sc[256];
    __shared__ u32 sfilled;
    if (threadIdx.x == 0) sfilled = 0;
    __syncthreads();
    for (int base = 0; base < LC; base += 256) {
        int idx = base + threadIdx.x;
        u32 flag = 0;
        if (idx < LC) {
            int loc = idx / C_CLS, c = idx - (idx / C_CLS) * C_CLS;
            float x = cls[(size_t)n * LC + (size_t)c * L_LOC + loc];
            flag = (sigmoidf_acc(x) > THRESH) ? 0u : 1u;
        }
        sc[threadIdx.x] = flag;
        __syncthreads();
        for (int off = 1; off < 256; off <<= 1) {
            u32 v = (threadIdx.x >= off) ? sc[threadIdx.x - off] : 0u;
            __syncthreads();
            sc[threadIdx.x] += v;
            __syncthreads();
        }
        u32 excl = sc[threadIdx.x] - flag;
        u32 pos = sfilled + excl;
        if (flag && pos < need) fillidx[(size_t)n * K_TOP + pos] = (u32)idx;
        __syncthreads();
        if (threadIdx.x == 0) sfilled += sc[255];
        __syncthreads();
        if (sfilled >= need) break;
    }
}

// --- kernel 7: per-image bitonic sort + decode/emit ---
__global__ __launch_bounds__(1024) void sort_emit_kernel(
        const u64* __restrict__ keys, const u32* __restrict__ cnt,
        const u32* __restrict__ meta, const u32* __restrict__ fillidx,
        const float* __restrict__ locations, const float* __restrict__ breg,
        const int* __restrict__ isz, float* __restrict__ out) {
    __shared__ u64 sk[CAP];
    const int n = blockIdx.x;
    const int tid = threadIdx.x;
    u32 M = cnt[n]; if (M > (u32)CAP) M = (u32)CAP;
    const u32 cand_total = meta[n * 4 + 1];
    const u32 cand_slots = cand_total < (u32)K_TOP ? cand_total : (u32)K_TOP;
    u32 n2 = 1024; while (n2 < M) n2 <<= 1;
    const u64* kb = keys + (size_t)n * CAP;
    for (u32 i = tid; i < n2; i += blockDim.x) sk[i] = (i < M) ? kb[i] : 0ull;
    __syncthreads();
    for (u32 k = 2; k <= n2; k <<= 1) {
        for (u32 j = k >> 1; j > 0; j >>= 1) {
            for (u32 i = tid; i < n2; i += blockDim.x) {
                u32 ixj = i ^ j;
                if (ixj > i) {
                    u64 a = sk[i], b = sk[ixj];
                    bool front = ((i & k) == 0);
                    if (front ? (a < b) : (a > b)) { sk[i] = b; sk[ixj] = a; }
                }
            }
            __syncthreads();
        }
    }
    float* ob = out;                                  // boxes  [N,K,4]
    float* os = out + (size_t)N_IMG * K_TOP * 4;      // scores [N,K]
    float* ol = os + (size_t)N_IMG * K_TOP;           // labels [N,K]
    float* ov = ol + (size_t)N_IMG * K_TOP;           // valid  [N,K]
    const float wimg = (float)isz[n * 2 + 1];
    const float himg = (float)isz[n * 2 + 0];
    const float* rn = breg + (size_t)n * 4 * L_LOC;
    for (int k = tid; k < K_TOP; k += blockDim.x) {
        size_t slot = (size_t)n * K_TOP + k;
        if ((u32)k < cand_slots) {
            u64 kk = sk[k];
            u32 vb = (u32)(kk >> 32);
            u32 idx = ~(u32)(kk & 0xFFFFFFFFull);
            float val = __uint_as_float(vb);
            int loc = (int)(idx / (u32)C_CLS);
            int c = (int)(idx - (u32)loc * (u32)C_CLS);
            float lx = locations[loc * 2 + 0], ly = locations[loc * 2 + 1];
            float r0 = rn[0 * L_LOC + loc], r1 = rn[1 * L_LOC + loc];
            float r2 = rn[2 * L_LOC + loc], r3 = rn[3 * L_LOC + loc];
            float x1 = lx - r0, y1 = ly - r1, x2 = lx + r2, y2 = ly + r3;
            x1 = fminf(fmaxf(x1, 0.0f), wimg - 1.0f);
            y1 = fminf(fmaxf(y1, 0.0f), himg - 1.0f);
            x2 = fminf(fmaxf(x2, 0.0f), wimg - 1.0f);
            y2 = fminf(fmaxf(y2, 0.0f), himg - 1.0f);
            float wsz = x2 - x1 + 1.0f, hsz = y2 - y1 + 1.0f;
            bool v = (val > 0.0f) && (wsz >= 0.0f) && (hsz >= 0.0f);  // MIN_SIZE = 0
            float vf = v ? 1.0f : 0.0f;
            ob[slot * 4 + 0] = x1 * vf;
            ob[slot * 4 + 1] = y1 * vf;
            ob[slot * 4 + 2] = x2 * vf;
            ob[slot * 4 + 3] = y2 * vf;
            os[slot] = v ? sqrtf(fmaxf(val, 0.0f)) : 0.0f;
            ol[slot] = (float)(c + 1);
            ov[slot] = vf;
        } else {
            u32 fi = fillidx[(size_t)n * K_TOP + (k - (int)cand_slots)];
            ob[slot * 4 + 0] = 0.0f; ob[slot * 4 + 1] = 0.0f;
            ob[slot * 4 + 2] = 0.0f; ob[slot * 4 + 3] = 0.0f;
            os[slot] = 0.0f;
            ol[slot] = (float)((int)(fi % (u32)C_CLS) + 1);
            ov[slot] = 0.0f;
        }
    }
}

extern "C" void kernel_launch(void* const* d_in, const int* in_sizes, int n_in,
                              void* d_out, int out_size, void* d_ws, size_t ws_size,
                              hipStream_t stream) {
    const float* locations = (const float*)d_in[0];
    const float* cls       = (const float*)d_in[1];
    const float* breg      = (const float*)d_in[2];
    const float* ctr       = (const float*)d_in[3];
    const int*   isz       = (const int*)d_in[4];
    float* out = (float*)d_out;

    char* ws = (char*)d_ws;
    u32* cnt   = (u32*)(ws + WS_CNT);
    u32* scnt  = (u32*)(ws + WS_SCNT);
    u32* oflow = (u32*)(ws + WS_OFLOW);
    u32* meta  = (u32*)(ws + WS_META);
    u32* Hsub  = (u32*)(ws + WS_HIST);   // slow path
    u64* keys2 = (u64*)(ws + WS_HIST);   // fast path (overlay; per-image exclusive)
    u32* spec  = (u32*)(ws + WS_SPEC);
    u64* keys  = (u64*)(ws + WS_KEYS);
    u32* fill  = (u32*)(ws + WS_FILL);
    float* sctr = (float*)(ws + WS_SCTR);
    float* xmin = (float*)(ws + WS_XMIN);

    zero_kernel<<<1, 128, 0, stream>>>((u32*)ws);
    prep_kernel<<<(N_IMG * L_LOC + 255) / 256, 256, 0, stream>>>(ctr, sctr, xmin, N_IMG * L_LOC);
    passA_kernel<<<dim3(128, N_IMG), 256, 0, stream>>>(cls, xmin, spec, scnt, oflow);
    filterB_kernel<<<N_IMG, 1024, 0, stream>>>(cls, sctr, spec, scnt, oflow, keys2, keys, cnt, meta);
    slow_hist_kernel<<<dim3(NBLK, N_IMG), 256, 0, stream>>>(cls, sctr, meta, Hsub);
    slow_scan_kernel<<<N_IMG, 256, 0, stream>>>(Hsub, meta);
    gather_slow_kernel<<<dim3(NBLK, N_IMG), 256, 0, stream>>>(cls, sctr, meta, cnt, keys);
    fallback_kernel<<<N_IMG, 256, 0, stream>>>(cls, meta, fill);
    sort_emit_kernel<<<N_IMG, 1024, 0, stream>>>(keys, cnt, meta, fill, locations, breg, isz, out);
}

// Round 6
// 104.612 us; speedup vs baseline: 3.7017x; 1.3998x over previous
//
#include <hip/hip_runtime.h>
#include <math.h>

typedef unsigned int u32;
typedef unsigned long long u64;

constexpr int N_IMG = 16;
constexpr int C_CLS = 80;
constexpr int H_DIM = 160;
constexpr int W_DIM = 160;
constexpr int L_LOC = H_DIM * W_DIM;   // 25600
constexpr int LC    = L_LOC * C_CLS;   // 2048000
constexpr int K_TOP = 1000;
constexpr int NB    = 1024;            // histogram buckets: (bits-KEY_BASE)>>16
constexpr int CAP   = 4096;            // sorted-candidate cap per image (32KB LDS)
constexpr int CAP_SPEC = 32768;        // speculative list cap per image
constexpr int GBUF  = 1024;            // passA per-block LDS buffer (u64)
constexpr float THRESH = 0.05f;
constexpr u32 KEY_BASE = 119u << 23;   // 0x3B800000
constexpr u32 T0_BITS  = 0x3F333333u;  // bits of 0.7f
constexpr float T0     = 0.7f;
constexpr float DELTA  = 0.05f;        // conservative slack in logit space
// buckets >= B_SAFE have lower bound > 0.7f, where spec is provably a superset
constexpr int B_SAFE  = ((0x3F340000u - KEY_BASE) >> 16);  // 948

// ---- workspace layout (bytes) ----
constexpr size_t WS_SCNT  = 0;                                       // N*4
constexpr size_t WS_OFLOW = 64;                                      // N*4
constexpr size_t WS_META  = 128;                                     // N*16 (.,.,done,.)
constexpr size_t WS_CTRL_WORDS = 128;                                // 512 B zeroed
constexpr size_t WS_GHIST = 512;                                     // 16*1024*4 = 64 KB
constexpr size_t WS_SPEC  = WS_GHIST + (size_t)N_IMG * NB * 4;       // 16*32768*8 = 4 MB
constexpr size_t WS_SCTR  = WS_SPEC + (size_t)N_IMG * CAP_SPEC * 8;  // N*L*4
constexpr size_t WS_XMIN  = WS_SCTR + (size_t)N_IMG * L_LOC * 4;     // N*L*4

__device__ inline float sigmoidf_acc(float x) { return 1.0f / (1.0f + expf(-x)); }

__device__ inline u32 score_bucket(u32 bits) {
    u32 b = (bits >= KEY_BASE) ? ((bits - KEY_BASE) >> 16) : 0u;
    return b > (u32)(NB - 1) ? (u32)(NB - 1) : b;
}

// ---- shared device helpers ----

// bitonic sort of sk[0..n2) descending (pads with 0 above M); barriers inside
__device__ inline void bitonic_desc(u64* sk, u32 M, int tid, int nthr) {
    u32 n2 = 1024; while (n2 < M) n2 <<= 1;
    for (u32 i = tid; i < n2; i += nthr) if (i >= M) sk[i] = 0ull;
    __syncthreads();
    for (u32 k = 2; k <= n2; k <<= 1) {
        for (u32 j = k >> 1; j > 0; j >>= 1) {
            for (u32 i = tid; i < n2; i += nthr) {
                u32 ixj = i ^ j;
                if (ixj > i) {
                    u64 a = sk[i], b = sk[ixj];
                    bool front = ((i & k) == 0);
                    if (front ? (a < b) : (a > b)) { sk[i] = b; sk[ixj] = a; }
                }
            }
            __syncthreads();
        }
    }
}

// decode + write the K output rows for image n
__device__ inline void emit_rows(int n, const u64* sk, u32 cand_slots, const u32* fill,
                                 const float* locations, const float* breg,
                                 const int* isz, float* out, int tid, int nthr) {
    float* ob = out;                                  // boxes  [N,K,4]
    float* os = out + (size_t)N_IMG * K_TOP * 4;      // scores [N,K]
    float* ol = os + (size_t)N_IMG * K_TOP;           // labels [N,K]
    float* ov = ol + (size_t)N_IMG * K_TOP;           // valid  [N,K]
    const float wimg = (float)isz[n * 2 + 1];
    const float himg = (float)isz[n * 2 + 0];
    const float* rn = breg + (size_t)n * 4 * L_LOC;
    for (int k = tid; k < K_TOP; k += nthr) {
        size_t slot = (size_t)n * K_TOP + k;
        if ((u32)k < cand_slots) {
            u64 kk = sk[k];
            u32 vb = (u32)(kk >> 32);
            u32 idx = ~(u32)(kk & 0xFFFFFFFFull);
            float val = __uint_as_float(vb);
            int loc = (int)(idx / (u32)C_CLS);
            int c = (int)(idx - (u32)loc * (u32)C_CLS);
            float lx = locations[loc * 2 + 0], ly = locations[loc * 2 + 1];
            float r0 = rn[0 * L_LOC + loc], r1 = rn[1 * L_LOC + loc];
            float r2 = rn[2 * L_LOC + loc], r3 = rn[3 * L_LOC + loc];
            float x1 = lx - r0, y1 = ly - r1, x2 = lx + r2, y2 = ly + r3;
            x1 = fminf(fmaxf(x1, 0.0f), wimg - 1.0f);
            y1 = fminf(fmaxf(y1, 0.0f), himg - 1.0f);
            x2 = fminf(fmaxf(x2, 0.0f), wimg - 1.0f);
            y2 = fminf(fmaxf(y2, 0.0f), himg - 1.0f);
            float wsz = x2 - x1 + 1.0f, hsz = y2 - y1 + 1.0f;
            bool v = (val > 0.0f) && (wsz >= 0.0f) && (hsz >= 0.0f);  // MIN_SIZE = 0
            float vf = v ? 1.0f : 0.0f;
            ob[slot * 4 + 0] = x1 * vf;
            ob[slot * 4 + 1] = y1 * vf;
            ob[slot * 4 + 2] = x2 * vf;
            ob[slot * 4 + 3] = y2 * vf;
            os[slot] = v ? sqrtf(fmaxf(val, 0.0f)) : 0.0f;
            ol[slot] = (float)(c + 1);
            ov[slot] = vf;
        } else {
            u32 fi = fill ? fill[k - (int)cand_slots] : 0u;
            ob[slot * 4 + 0] = 0.0f; ob[slot * 4 + 1] = 0.0f;
            ob[slot * 4 + 2] = 0.0f; ob[slot * 4 + 3] = 0.0f;
            os[slot] = 0.0f;
            ol[slot] = (float)((int)(fi % (u32)C_CLS) + 1);
            ov[slot] = 0.0f;
        }
    }
}

// --- kernel 1: zero control+ghist, sigmoid(centerness), per-location logit threshold ---
__global__ void prep_kernel(const float* __restrict__ ctr, float* __restrict__ sctr,
                            float* __restrict__ xmin, u32* __restrict__ ws32) {
    int i = blockIdx.x * blockDim.x + threadIdx.x;
    if (i < (int)WS_CTRL_WORDS) ws32[i] = 0u;
    if (i < N_IMG * NB) ws32[WS_GHIST / 4 + i] = 0u;   // zero ghist
    if (i >= N_IMG * L_LOC) return;
    float s = sigmoidf_acc(ctr[i]);
    sctr[i] = s;
    float t = T0 / s;                       // need sigmoid(x) >= t for score >= T0
    float xm;
    if (t >= 1.0f) xm = 3.0e38f;            // impossible at this location
    else xm = logf(t / (1.0f - t)) - DELTA; // logit(t) with conservative slack
    xmin[i] = xm;
}

// --- kernel 2 (hot pass): compare per element; exact score + hist for survivors ---
__global__ __launch_bounds__(256) void passA_kernel(
        const float* __restrict__ cls, const float* __restrict__ xmin,
        const float* __restrict__ sctr, u64* __restrict__ spec,
        u32* __restrict__ scnt, u32* __restrict__ oflow, u32* __restrict__ ghist) {
    __shared__ u32 lh[NB];
    __shared__ u64 sbuf[GBUF];
    __shared__ u32 lcnt, gbase, lof;
    const int n = blockIdx.y;
    for (int b = threadIdx.x; b < NB; b += 256) lh[b] = 0u;
    if (threadIdx.x == 0) { lcnt = 0; lof = 0; }
    __syncthreads();
    const float4* cls4 = reinterpret_cast<const float4*>(cls + (size_t)n * LC);
    const float* xm_n = xmin + (size_t)n * L_LOC;
    const float* sc_n = sctr + (size_t)n * L_LOC;
    const u32 ngroups = LC / 4;
    const u32 stride = gridDim.x * blockDim.x;
    for (u32 g = blockIdx.x * blockDim.x + threadIdx.x; g < ngroups; g += stride) {
        u32 f = g * 4;
        u32 c = f / (u32)L_LOC;
        u32 loc = f % (u32)L_LOC;           // float4 never crosses a class plane (L%4==0)
        float4 x = cls4[g];
        float4 m = *reinterpret_cast<const float4*>(xm_n + loc);
        u32 base = loc * (u32)C_CLS + c;    // refidx for j=0; +C_CLS per j
        float xs[4] = {x.x, x.y, x.z, x.w};
        float ms[4] = {m.x, m.y, m.z, m.w};
#pragma unroll
        for (int j = 0; j < 4; ++j) {
            if (xs[j] >= ms[j]) {
                float s = sigmoidf_acc(xs[j]);
                float scr = s * sc_n[loc + j];           // exact reference-formula score
                u32 bits = __float_as_uint(scr);
                atomicAdd(&lh[score_bucket(bits)], 1u);
                u32 p = atomicAdd(&lcnt, 1u);
                if (p < (u32)GBUF)
                    sbuf[p] = ((u64)bits << 32) | (u32)(~(base + (u32)j * (u32)C_CLS));
                else lof = 1u;
            }
        }
    }
    __syncthreads();
    // sparse merge of per-block hist (survivors only -> few non-zero buckets)
    u32* hn = ghist + (size_t)n * NB;
    for (int b = threadIdx.x; b < NB; b += 256) {
        u32 v = lh[b];
        if (v) atomicAdd(&hn[b], v);
    }
    u32 m_ = lcnt > (u32)GBUF ? (u32)GBUF : lcnt;
    if (threadIdx.x == 0) {
        gbase = m_ ? atomicAdd(&scnt[n], m_) : 0u;
        if (lof || lcnt > (u32)GBUF) atomicOr(&oflow[n], 1u);
        if (m_ && gbase + m_ > (u32)CAP_SPEC) atomicOr(&oflow[n], 1u);
    }
    __syncthreads();
    u64* sp = spec + (size_t)n * CAP_SPEC;
    for (u32 i = threadIdx.x; i < m_; i += blockDim.x) {
        u32 pos = gbase + i;
        if (pos < (u32)CAP_SPEC) sp[pos] = sbuf[i];
    }
}

// --- kernel 3 (FAST): suffix-scan hist -> cutoff; filter spec; sort; emit ---
__global__ __launch_bounds__(1024) void fastB_kernel(
        const u32* __restrict__ ghist, const u32* __restrict__ scnt,
        const u32* __restrict__ oflow, const u64* __restrict__ spec,
        u32* __restrict__ meta, const float* __restrict__ locations,
        const float* __restrict__ breg, const int* __restrict__ isz,
        float* __restrict__ out) {
    __shared__ u32 sfx[NB];
    __shared__ u64 sk[CAP];
    __shared__ u32 s_b, s_lcnt;
    const int n = blockIdx.x;
    const int tid = threadIdx.x;
    sfx[tid] = ghist[(size_t)n * NB + tid];
    if (tid == 0) { s_b = 0xFFFFFFFFu; s_lcnt = 0; }
    __syncthreads();
    // suffix sum: sfx[b] = count of spec with bucket >= b
    for (u32 off = 1; off < (u32)NB; off <<= 1) {
        u32 add = (tid + off < (u32)NB) ? sfx[tid + off] : 0u;
        __syncthreads();
        sfx[tid] += add;
        __syncthreads();
    }
    // b* = highest bucket with cumulative >= K
    if (sfx[tid] >= (u32)K_TOP && (tid == NB - 1 || sfx[tid + 1] < (u32)K_TOP))
        s_b = (u32)tid;
    __syncthreads();
    u32 bstar = s_b;
    bool valid = (bstar != 0xFFFFFFFFu) && (bstar >= (u32)B_SAFE) &&
                 (sfx[bstar] <= (u32)CAP) && (oflow[n] == 0u) &&
                 (scnt[n] <= (u32)CAP_SPEC);
    if (!valid) return;                      // meta.done stays 0 -> slowC handles
    if (tid == 0) meta[n * 4 + 2] = 1u;
    const u32 keymin = KEY_BASE + (bstar << 16);
    const u32 M = scnt[n];
    const u64* sp = spec + (size_t)n * CAP_SPEC;
    for (u32 i = tid; i < M; i += 1024) {
        u64 e = sp[i];
        if ((u32)(e >> 32) >= keymin) {
            u32 p = atomicAdd(&s_lcnt, 1u);
            if (p < (u32)CAP) sk[p] = e;
        }
    }
    __syncthreads();
    u32 Mk = s_lcnt;                         // == sfx[bstar] <= CAP, >= K
    bitonic_desc(sk, Mk, tid, 1024);
    emit_rows(n, sk, (u32)K_TOP, nullptr, locations, breg, isz, out, tid, 1024);
}

// --- kernel 4 (SLOW, gated; never taken in practice): full per-image pipeline ---
__global__ __launch_bounds__(1024) void slowC_kernel(
        const float* __restrict__ cls, const float* __restrict__ sctr,
        const u32* __restrict__ meta, const float* __restrict__ locations,
        const float* __restrict__ breg, const int* __restrict__ isz,
        float* __restrict__ out) {
    const int n = blockIdx.x;
    if (meta[n * 4 + 2] != 0u) return;
    __shared__ u32 lh[NB];                   // hist -> suffix -> scan scratch
    __shared__ u64 sk[CAP];
    __shared__ u32 fill[K_TOP];
    __shared__ u32 s_b, s_lcnt, s_filled;
    const int tid = threadIdx.x;
    lh[tid] = 0u;
    if (tid == 0) { s_b = 0xFFFFFFFFu; s_lcnt = 0; s_filled = 0; }
    __syncthreads();
    const float* cls_n = cls + (size_t)n * LC;
    const float* sc_n = sctr + (size_t)n * L_LOC;
    // phase 1: full histogram (coalesced over [C][L] plane order)
    for (u32 f = tid; f < (u32)LC; f += 1024) {
        float s = sigmoidf_acc(cls_n[f]);
        if (s > THRESH) {
            float scr = s * sc_n[f % (u32)L_LOC];
            atomicAdd(&lh[score_bucket(__float_as_uint(scr))], 1u);
        }
    }
    __syncthreads();
    // phase 2: suffix sums + cutoff
    for (u32 off = 1; off < (u32)NB; off <<= 1) {
        u32 add = (tid + off < (u32)NB) ? lh[tid + off] : 0u;
        __syncthreads();
        lh[tid] += add;
        __syncthreads();
    }
    if (lh[tid] >= (u32)K_TOP && (tid == NB - 1 || lh[tid + 1] < (u32)K_TOP))
        s_b = (u32)tid;
    __syncthreads();
    const u32 total = lh[0];
    const u32 keymin = (s_b != 0xFFFFFFFFu) ? (KEY_BASE + (s_b << 16)) : 0u;
    __syncthreads();
    // phase 3: gather candidates >= keymin
    for (u32 f = tid; f < (u32)LC; f += 1024) {
        float s = sigmoidf_acc(cls_n[f]);
        if (s > THRESH) {
            u32 loc = f % (u32)L_LOC;
            u32 c = f / (u32)L_LOC;
            float scr = s * sc_n[loc];
            u32 bits = __float_as_uint(scr);
            if (bits >= keymin) {
                u32 p = atomicAdd(&s_lcnt, 1u);
                if (p < (u32)CAP)
                    sk[p] = ((u64)bits << 32) | (u32)(~(loc * (u32)C_CLS + c));
            }
        }
    }
    __syncthreads();
    u32 M = s_lcnt > (u32)CAP ? (u32)CAP : s_lcnt;
    u32 cand_slots = total < (u32)K_TOP ? total : (u32)K_TOP;
    // phase 4: fallback fill list (smallest non-candidate flat (L,C) indices)
    if (total < (u32)K_TOP) {
        const u32 need = (u32)K_TOP - total;
        for (u32 basei = 0; basei < (u32)LC; basei += 1024) {
            u32 idx = basei + tid;
            u32 flag = 0;
            if (idx < (u32)LC) {
                u32 loc = idx / (u32)C_CLS;
                u32 c = idx - loc * (u32)C_CLS;
                float x = cls_n[(size_t)c * L_LOC + loc];
                flag = (sigmoidf_acc(x) > THRESH) ? 0u : 1u;
            }
            lh[tid] = flag;
            __syncthreads();
            for (u32 off = 1; off < 1024; off <<= 1) {
                u32 v = (tid >= (int)off) ? lh[tid - off] : 0u;
                __syncthreads();
                lh[tid] += v;
                __syncthreads();
            }
            u32 excl = lh[tid] - flag;
            u32 pos = s_filled + excl;
            if (flag && pos < need) fill[pos] = idx;
            __syncthreads();
            if (tid == 0) s_filled += lh[1023];
            __syncthreads();
            if (s_filled >= need) break;
        }
    }
    // phase 5+6: sort + emit
    bitonic_desc(sk, M, tid, 1024);
    emit_rows(n, sk, cand_slots, fill, locations, breg, isz, out, tid, 1024);
}

extern "C" void kernel_launch(void* const* d_in, const int* in_sizes, int n_in,
                              void* d_out, int out_size, void* d_ws, size_t ws_size,
                              hipStream_t stream) {
    const float* locations = (const float*)d_in[0];
    const float* cls       = (const float*)d_in[1];
    const float* breg      = (const float*)d_in[2];
    const float* ctr       = (const float*)d_in[3];
    const int*   isz       = (const int*)d_in[4];
    float* out = (float*)d_out;

    char* ws = (char*)d_ws;
    u32* ws32  = (u32*)ws;
    u32* scnt  = (u32*)(ws + WS_SCNT);
    u32* oflow = (u32*)(ws + WS_OFLOW);
    u32* meta  = (u32*)(ws + WS_META);
    u32* ghist = (u32*)(ws + WS_GHIST);
    u64* spec  = (u64*)(ws + WS_SPEC);
    float* sctr = (float*)(ws + WS_SCTR);
    float* xmin = (float*)(ws + WS_XMIN);

    prep_kernel<<<(N_IMG * L_LOC + 255) / 256, 256, 0, stream>>>(ctr, sctr, xmin, ws32);
    passA_kernel<<<dim3(128, N_IMG), 256, 0, stream>>>(cls, xmin, sctr, spec, scnt, oflow, ghist);
    fastB_kernel<<<N_IMG, 1024, 0, stream>>>(ghist, scnt, oflow, spec, meta,
                                             locations, breg, isz, out);
    slowC_kernel<<<N_IMG, 1024, 0, stream>>>(cls, sctr, meta, locations, breg, isz, out);
}